// Round 5
// baseline (300.701 us; speedup 1.0000x reference)
//
#include <hip/hip_runtime.h>

// BusStopGNN round 5: matmul kernels eliminated via linearity:
//   Ahat (H W) = (Ahat H) W  -> aggregate-then-transform, fused in one kernel
// while the node's 64-vector is wave-resident (z staged in per-wave LDS,
// W column register-resident). Layer 2 also fuses the Wp head reduction.
// CSR build via two-level counting sort unchanged.

#define GNN_N 100000
#define GNN_E 1600000
#define NBUCK 391   // ceil(N/256), bucket = dst >> 8
#define NBLK  256
#define EPB   6250  // E / NBLK

// ---- Pass 1: per-block LDS histogram over dst buckets ----
__global__ __launch_bounds__(256) void k_hist(const int* __restrict__ dst,
                                              int* __restrict__ hist) {
    __shared__ int h[NBUCK];
    for (int i = threadIdx.x; i < NBUCK; i += 256) h[i] = 0;
    __syncthreads();
    int b = blockIdx.x;
    int e0 = b * EPB, e1 = min(e0 + EPB, GNN_E);
    for (int e = e0 + threadIdx.x; e < e1; e += 256)
        atomicAdd(&h[dst[e] >> 8], 1);
    __syncthreads();
    for (int i = threadIdx.x; i < NBUCK; i += 256)
        hist[b * NBUCK + i] = h[i];
}

// ---- Pass 2: column scan + bucket bases ----
__global__ __launch_bounds__(512) void k_colscan(int* __restrict__ hist,
                                                 int* __restrict__ bbase) {
    __shared__ int tot[NBUCK];
    int k = threadIdx.x;
    if (k < NBUCK) {
        int run = 0;
        for (int b = 0; b < NBLK; ++b) {
            int idx = b * NBUCK + k;
            int t = hist[idx];
            hist[idx] = run;
            run += t;
        }
        tot[k] = run;
    }
    __syncthreads();
    if (threadIdx.x == 0) {
        int run = 0;
        for (int i = 0; i < NBUCK; ++i) { int t = tot[i]; tot[i] = run; run += t; }
    }
    __syncthreads();
    if (k < NBUCK) bbase[k] = tot[k];
    if (threadIdx.x == 0) bbase[NBUCK] = GNN_E;
}

// ---- Pass 3: partition edges into bucket regions; pack (dst&255)<<17 | src ----
__global__ __launch_bounds__(256) void k_part(const int* __restrict__ src,
                                              const int* __restrict__ dst,
                                              const int* __restrict__ hist,
                                              const int* __restrict__ bbase,
                                              unsigned int* __restrict__ part) {
    __shared__ int off[NBUCK];
    int b = blockIdx.x;
    for (int i = threadIdx.x; i < NBUCK; i += 256)
        off[i] = bbase[i] + hist[b * NBUCK + i];
    __syncthreads();
    int e0 = b * EPB, e1 = min(e0 + EPB, GNN_E);
    for (int e = e0 + threadIdx.x; e < e1; e += 256) {
        int d = dst[e], s = src[e];
        int slot = atomicAdd(&off[d >> 8], 1);
        part[slot] = ((unsigned int)(d & 255) << 17) | (unsigned int)s;
    }
}

// ---- Pass 4: per-bucket counting sort -> csr, rowptr, deg, dis ----
__global__ __launch_bounds__(256) void k_bsort(const unsigned int* __restrict__ part,
                                               const int* __restrict__ bbase,
                                               int* __restrict__ csr,
                                               int* __restrict__ rowptr,
                                               int* __restrict__ deg,
                                               float* __restrict__ dis) {
    __shared__ int cnt[256];
    __shared__ int pos[256];
    int k = blockIdx.x;
    int t = threadIdx.x;
    cnt[t] = 0;
    __syncthreads();
    int e0 = bbase[k], e1 = bbase[k + 1];
    for (int e = e0 + t; e < e1; e += 256)
        atomicAdd(&cnt[part[e] >> 17], 1);
    __syncthreads();
    if (t == 0) {
        int run = 0;
        for (int i = 0; i < 256; ++i) { int c = cnt[i]; pos[i] = run; run += c; }
    }
    __syncthreads();
    int node = k * 256 + t;
    if (node < GNN_N) {
        rowptr[node] = e0 + pos[t];
        deg[node]    = cnt[t];
        dis[node]    = rsqrtf((float)cnt[t] + 1.0f);
    }
    __syncthreads();
    for (int e = e0 + t; e < e1; e += 256) {
        unsigned int p = part[e];
        int slot = e0 + atomicAdd(&pos[p >> 17], 1);
        csr[slot] = (int)(p & 0x1FFFF);
    }
}

// ---- pre-scale: Xs[i] = x[i] * dis[i]  (one float4 per thread) ----
__global__ __launch_bounds__(256) void k_prescale(const float* __restrict__ x,
                                                  const float* __restrict__ dis,
                                                  float* __restrict__ Xs, int n) {
    int t = blockIdx.x * 256 + threadIdx.x;
    if (t >= n * 16) return;
    int i = t >> 4;
    float4 v = ((const float4*)x)[t];
    float d = dis[i];
    v.x *= d; v.y *= d; v.z *= d; v.w *= d;
    ((float4*)Xs)[t] = v;
}

// ---- fused layer: gather + (z @ W + b) + relu [+ head | * dis] ----
// Wave per node (grid-stride). lane = channel. Input table Hs is row-prescaled
// by dis. z = dis[i]*(sum_{s in N(i)} Hs[s] + Hs[i]); r = relu(z@W + b).
// HEAD=false: out[i][lane] = r*dis[i] (pre-scaled for next layer's gather).
// HEAD=true:  out[i] = dot(r, Wp) + bp (wave shfl reduction).
template<bool HEAD>
__global__ __launch_bounds__(256, 1) void k_layer(
        const float* __restrict__ Hs, const int* __restrict__ csr,
        const int* __restrict__ rowptr, const int* __restrict__ deg,
        const float* __restrict__ dis, const float* __restrict__ W,
        const float* __restrict__ bias, const float* __restrict__ Wp,
        const float* __restrict__ bp, float* __restrict__ out, int n) {
    __shared__ float Ws[64 * 64];   // W[k][j]
    __shared__ float Zs[4][64];     // per-wave z staging
    int tid = threadIdx.x;
    for (int i = tid; i < 1024; i += 256)
        ((float4*)Ws)[i] = ((const float4*)W)[i];
    __syncthreads();
    int lane = tid & 63, wid = tid >> 6;
    float wcol[64];                 // my output column of W (static indexing only)
#pragma unroll
    for (int k = 0; k < 64; ++k) wcol[k] = Ws[k * 64 + lane];  // conflict-free
    float bj = bias[lane];
    float wp = 0.f, bp0 = 0.f;
    if constexpr (HEAD) { wp = Wp[lane]; bp0 = bp[0]; }
    int stride = gridDim.x * 4;
    for (int node = blockIdx.x * 4 + wid; node < n; node += stride) {
        int base = rowptr[node];
        int cnt = deg[node];
        float dd = dis[node];
        float acc = 0.0f;
        int j = 0;
        for (; j + 8 <= cnt; j += 8) {
            int s0 = csr[base + j + 0], s1 = csr[base + j + 1];
            int s2 = csr[base + j + 2], s3 = csr[base + j + 3];
            int s4 = csr[base + j + 4], s5 = csr[base + j + 5];
            int s6 = csr[base + j + 6], s7 = csr[base + j + 7];
            acc += Hs[(size_t)s0 * 64 + lane] + Hs[(size_t)s1 * 64 + lane]
                 + Hs[(size_t)s2 * 64 + lane] + Hs[(size_t)s3 * 64 + lane]
                 + Hs[(size_t)s4 * 64 + lane] + Hs[(size_t)s5 * 64 + lane]
                 + Hs[(size_t)s6 * 64 + lane] + Hs[(size_t)s7 * 64 + lane];
        }
        for (; j + 4 <= cnt; j += 4) {
            int s0 = csr[base + j + 0], s1 = csr[base + j + 1];
            int s2 = csr[base + j + 2], s3 = csr[base + j + 3];
            acc += Hs[(size_t)s0 * 64 + lane] + Hs[(size_t)s1 * 64 + lane]
                 + Hs[(size_t)s2 * 64 + lane] + Hs[(size_t)s3 * 64 + lane];
        }
        for (; j < cnt; ++j)
            acc += Hs[(size_t)csr[base + j] * 64 + lane];
        float z = dd * (acc + Hs[(size_t)node * 64 + lane]);
        // stage z for wave-wide broadcast (same-wave DS ops are in-order;
        // lgkmcnt(0) guarantees the write landed before the reads issue)
        Zs[wid][lane] = z;
        asm volatile("s_waitcnt lgkmcnt(0)" ::: "memory");
        float r0 = 0.f, r1 = 0.f, r2 = 0.f, r3 = 0.f;  // 4 chains: break FMA latency
#pragma unroll
        for (int k4 = 0; k4 < 16; ++k4) {
            float4 zq = *(const float4*)&Zs[wid][k4 * 4];  // broadcast read
            r0 += zq.x * wcol[4 * k4 + 0];
            r1 += zq.y * wcol[4 * k4 + 1];
            r2 += zq.z * wcol[4 * k4 + 2];
            r3 += zq.w * wcol[4 * k4 + 3];
        }
        float r = fmaxf((r0 + r1) + (r2 + r3) + bj, 0.0f);
        if constexpr (HEAD) {
            float s = r * wp;
#pragma unroll
            for (int m = 32; m >= 1; m >>= 1) s += __shfl_xor(s, m);
            if (lane == 0) out[node] = s + bp0;
        } else {
            out[(size_t)node * 64 + lane] = r * dd;  // pre-scale for next layer
        }
    }
}

extern "C" void kernel_launch(void* const* d_in, const int* in_sizes, int n_in,
                              void* d_out, int out_size, void* d_ws, size_t ws_size,
                              hipStream_t stream) {
    const float* x  = (const float*)d_in[0];
    const int*   ei = (const int*)d_in[1];
    const float* W1 = (const float*)d_in[2];
    const float* b1 = (const float*)d_in[3];
    const float* W2 = (const float*)d_in[4];
    const float* b2 = (const float*)d_in[5];
    const float* Wp = (const float*)d_in[6];
    const float* bp = (const float*)d_in[7];
    float* out = (float*)d_out;

    const int N = GNN_N, E = GNN_E;
    const int* srcv = ei;
    const int* dstv = ei + E;

    // workspace layout (bytes):
    //   hist   @ 0         : NBLK*NBUCK ints
    //   bbase  @ 400,896   : 392 ints
    //   rowptr @ 402,944   : N ints
    //   deg    @ 802,944   : N ints
    //   dis    @ 1,202,944 : N floats
    //   csr    @ 1,603,584 : E ints
    //   bufA   @ 8,003,584 : N*64 floats (Xs = x*dis)
    //   bufB   @ 33,603,584: N*64 floats (h1s = h1*dis)
    //   part   @ 33,603,584: E u32 -- aliases bufB (part dead before bufB written)
    char* ws = (char*)d_ws;
    int*   hist   = (int*)(ws + 0);
    int*   bbase  = (int*)(ws + 400896);
    int*   rowptr = (int*)(ws + 402944);
    int*   deg    = (int*)(ws + 802944);
    float* dis    = (float*)(ws + 1202944);
    int*   csr    = (int*)(ws + 1603584);
    float* bufA   = (float*)(ws + 8003584);
    float* bufB   = (float*)(ws + 33603584);
    unsigned int* part = (unsigned int*)(ws + 33603584);

    // CSR build
    k_hist   <<<NBLK, 256, 0, stream>>>(dstv, hist);
    k_colscan<<<1, 512, 0, stream>>>(hist, bbase);
    k_part   <<<NBLK, 256, 0, stream>>>(srcv, dstv, hist, bbase, part);
    k_bsort  <<<NBUCK, 256, 0, stream>>>(part, bbase, csr, rowptr, deg, dis);

    // pre-scale input
    k_prescale<<<(N * 16 + 255) / 256, 256, 0, stream>>>(x, dis, bufA, N);

    // layer 1 (fused gather+transform), writes h1*dis
    k_layer<false><<<4096, 256, 0, stream>>>(bufA, csr, rowptr, deg, dis,
                                             W1, b1, nullptr, nullptr, bufB, N);
    // layer 2 + head (fused)
    k_layer<true><<<4096, 256, 0, stream>>>(bufB, csr, rowptr, deg, dis,
                                            W2, b2, Wp, bp, out, N);
}

// Round 6
// 217.162 us; speedup vs baseline: 1.3847x; 1.3847x over previous
//
#include <hip/hip_runtime.h>

// BusStopGNN round 6: un-fused lean pipeline.
//  - mm64: round-4 tile with "#pragma unroll 1" on k-loop (round-4 full unroll
//    -> VGPR 256, 9% occupancy, 80us). dis folded into epilogue.
//  - gather: float4-per-lane (lane = channel-quad x edge-slot) -> 4x bytes in
//    flight per vmem instruction; no LDS, low VGPR, max occupancy.
//  - head fused into gather-2 (shfl reduce).
// CSR build via two-level counting sort unchanged.

#define GNN_N 100000
#define GNN_E 1600000
#define NBUCK 391   // ceil(N/256), bucket = dst >> 8
#define NBLK  256
#define EPB   6250  // E / NBLK

// ---- Pass 1: per-block LDS histogram over dst buckets ----
__global__ __launch_bounds__(256) void k_hist(const int* __restrict__ dst,
                                              int* __restrict__ hist) {
    __shared__ int h[NBUCK];
    for (int i = threadIdx.x; i < NBUCK; i += 256) h[i] = 0;
    __syncthreads();
    int b = blockIdx.x;
    int e0 = b * EPB, e1 = min(e0 + EPB, GNN_E);
    for (int e = e0 + threadIdx.x; e < e1; e += 256)
        atomicAdd(&h[dst[e] >> 8], 1);
    __syncthreads();
    for (int i = threadIdx.x; i < NBUCK; i += 256)
        hist[b * NBUCK + i] = h[i];
}

// ---- Pass 2: column scan + bucket bases ----
__global__ __launch_bounds__(512) void k_colscan(int* __restrict__ hist,
                                                 int* __restrict__ bbase) {
    __shared__ int tot[NBUCK];
    int k = threadIdx.x;
    if (k < NBUCK) {
        int run = 0;
        for (int b = 0; b < NBLK; ++b) {
            int idx = b * NBUCK + k;
            int t = hist[idx];
            hist[idx] = run;
            run += t;
        }
        tot[k] = run;
    }
    __syncthreads();
    if (threadIdx.x == 0) {
        int run = 0;
        for (int i = 0; i < NBUCK; ++i) { int t = tot[i]; tot[i] = run; run += t; }
    }
    __syncthreads();
    if (k < NBUCK) bbase[k] = tot[k];
    if (threadIdx.x == 0) bbase[NBUCK] = GNN_E;
}

// ---- Pass 3: partition edges into bucket regions; pack (dst&255)<<17 | src ----
__global__ __launch_bounds__(256) void k_part(const int* __restrict__ src,
                                              const int* __restrict__ dst,
                                              const int* __restrict__ hist,
                                              const int* __restrict__ bbase,
                                              unsigned int* __restrict__ part) {
    __shared__ int off[NBUCK];
    int b = blockIdx.x;
    for (int i = threadIdx.x; i < NBUCK; i += 256)
        off[i] = bbase[i] + hist[b * NBUCK + i];
    __syncthreads();
    int e0 = b * EPB, e1 = min(e0 + EPB, GNN_E);
    for (int e = e0 + threadIdx.x; e < e1; e += 256) {
        int d = dst[e], s = src[e];
        int slot = atomicAdd(&off[d >> 8], 1);
        part[slot] = ((unsigned int)(d & 255) << 17) | (unsigned int)s;
    }
}

// ---- Pass 4: per-bucket counting sort -> csr, rowptr, deg, dis ----
__global__ __launch_bounds__(256) void k_bsort(const unsigned int* __restrict__ part,
                                               const int* __restrict__ bbase,
                                               int* __restrict__ csr,
                                               int* __restrict__ rowptr,
                                               int* __restrict__ deg,
                                               float* __restrict__ dis) {
    __shared__ int cnt[256];
    __shared__ int pos[256];
    int k = blockIdx.x;
    int t = threadIdx.x;
    cnt[t] = 0;
    __syncthreads();
    int e0 = bbase[k], e1 = bbase[k + 1];
    for (int e = e0 + t; e < e1; e += 256)
        atomicAdd(&cnt[part[e] >> 17], 1);
    __syncthreads();
    if (t == 0) {
        int run = 0;
        for (int i = 0; i < 256; ++i) { int c = cnt[i]; pos[i] = run; run += c; }
    }
    __syncthreads();
    int node = k * 256 + t;
    if (node < GNN_N) {
        rowptr[node] = e0 + pos[t];
        deg[node]    = cnt[t];
        dis[node]    = rsqrtf((float)cnt[t] + 1.0f);
    }
    __syncthreads();
    for (int e = e0 + t; e < e1; e += 256) {
        unsigned int p = part[e];
        int slot = e0 + atomicAdd(&pos[p >> 17], 1);
        csr[slot] = (int)(p & 0x1FFFF);
    }
}

// ---- tiled 64x64 matmul, dis epilogue: Y[row] = (X@W)[row]*dis[row] ----
// 64 rows/block; thread (ti,tj): rows ti*4..+3, col-quad tj. k-loop kept
// rolled (#pragma unroll 1) to bound live LDS loads -> no VGPR blowup.
__global__ __launch_bounds__(256) void k_mm64(const float* __restrict__ X,
                                              const float* __restrict__ W,
                                              const float* __restrict__ dis,
                                              float* __restrict__ Y, int n) {
    __shared__ float  Xs[64][68];
    __shared__ float4 Wsh[64 * 16];
    int tid = threadIdx.x;
    int base = blockIdx.x * 64;
    for (int i = tid; i < 1024; i += 256)
        Wsh[i] = ((const float4*)W)[i];
#pragma unroll
    for (int i = 0; i < 4; ++i) {
        int g = i * 256 + tid;
        int r = g >> 4, c4 = g & 15;
        int row = base + r;
        float4 v = (row < n) ? ((const float4*)(X + (size_t)row * 64))[c4]
                             : make_float4(0.f, 0.f, 0.f, 0.f);
        *(float4*)&Xs[r][c4 * 4] = v;
    }
    __syncthreads();
    int tj = tid & 15;
    int ti = tid >> 4;
    float4 a0 = {0,0,0,0}, a1 = {0,0,0,0}, a2 = {0,0,0,0}, a3 = {0,0,0,0};
#pragma unroll 1
    for (int k4 = 0; k4 < 16; ++k4) {
        float4 x0 = *(const float4*)&Xs[ti * 4 + 0][k4 * 4];
        float4 x1 = *(const float4*)&Xs[ti * 4 + 1][k4 * 4];
        float4 x2 = *(const float4*)&Xs[ti * 4 + 2][k4 * 4];
        float4 x3 = *(const float4*)&Xs[ti * 4 + 3][k4 * 4];
        float4 w0 = Wsh[(k4 * 4 + 0) * 16 + tj];
        float4 w1 = Wsh[(k4 * 4 + 1) * 16 + tj];
        float4 w2 = Wsh[(k4 * 4 + 2) * 16 + tj];
        float4 w3 = Wsh[(k4 * 4 + 3) * 16 + tj];
#define FMA4(A, XV)                                                      \
        A.x += XV.x * w0.x + XV.y * w1.x + XV.z * w2.x + XV.w * w3.x;    \
        A.y += XV.x * w0.y + XV.y * w1.y + XV.z * w2.y + XV.w * w3.y;    \
        A.z += XV.x * w0.z + XV.y * w1.z + XV.z * w2.z + XV.w * w3.z;    \
        A.w += XV.x * w0.w + XV.y * w1.w + XV.z * w2.w + XV.w * w3.w;
        FMA4(a0, x0) FMA4(a1, x1) FMA4(a2, x2) FMA4(a3, x3)
#undef FMA4
    }
#pragma unroll
    for (int q = 0; q < 4; ++q) {
        int row = base + ti * 4 + q;
        if (row < n) {
            float d = dis[row];
            float4 a = (q == 0) ? a0 : (q == 1) ? a1 : (q == 2) ? a2 : a3;
            a.x *= d; a.y *= d; a.z *= d; a.w *= d;
            ((float4*)(Y + (size_t)row * 64))[tj] = a;
        }
    }
}

// ---- gather, float4 lanes: lane = (channel-quad q, edge-slot s) ----
// Wave per node. Per main-loop iter a wave fetches 4 full 256B rows with 1
// vmem instruction per lane (16B) -> 4x bytes in flight vs scalar version.
// out = relu( dis*(sum + self) + b ); HEAD adds fused Wp reduction.
template<bool HEAD>
__global__ __launch_bounds__(256) void k_gather4(
        const float* __restrict__ Hs, const int* __restrict__ csr,
        const int* __restrict__ rowptr, const int* __restrict__ deg,
        const float* __restrict__ dis, const float* __restrict__ bias,
        const float* __restrict__ Wp, const float* __restrict__ bp,
        float* __restrict__ out, int n) {
    int tid = threadIdx.x;
    int lane = tid & 63;
    int q = lane & 15;        // channel quad: floats q*4..q*4+3
    int slot = lane >> 4;     // edge slot 0..3
    int node = blockIdx.x * 4 + (tid >> 6);
    if (node >= n) return;
    int base = rowptr[node];
    int cnt  = deg[node];
    float dd = dis[node];
    float4 a0 = {0,0,0,0}, a1 = {0,0,0,0};
    int j = 0;
    for (; j + 8 <= cnt; j += 8) {   // 8 rows (2KB) in flight per wave
        int sA = csr[base + j + slot];
        int sB = csr[base + j + 4 + slot];
        float4 vA = ((const float4*)(Hs + (size_t)sA * 64))[q];
        float4 vB = ((const float4*)(Hs + (size_t)sB * 64))[q];
        a0.x += vA.x; a0.y += vA.y; a0.z += vA.z; a0.w += vA.w;
        a1.x += vB.x; a1.y += vB.y; a1.z += vB.z; a1.w += vB.w;
    }
    if (j + 4 <= cnt) {
        int s = csr[base + j + slot];
        float4 v = ((const float4*)(Hs + (size_t)s * 64))[q];
        a0.x += v.x; a0.y += v.y; a0.z += v.z; a0.w += v.w;
        j += 4;
    }
    int rem = cnt - j;               // 0..3 masked tail
    if (slot < rem) {
        int s = csr[base + j + slot];
        float4 v = ((const float4*)(Hs + (size_t)s * 64))[q];
        a1.x += v.x; a1.y += v.y; a1.z += v.z; a1.w += v.w;
    }
    float4 acc;
    acc.x = a0.x + a1.x; acc.y = a0.y + a1.y;
    acc.z = a0.z + a1.z; acc.w = a0.w + a1.w;
    // combine the 4 edge-slots (lanes l, l^16, l^32, l^48)
#pragma unroll
    for (int m = 16; m <= 32; m <<= 1) {
        acc.x += __shfl_xor(acc.x, m);
        acc.y += __shfl_xor(acc.y, m);
        acc.z += __shfl_xor(acc.z, m);
        acc.w += __shfl_xor(acc.w, m);
    }
    float4 self = ((const float4*)(Hs + (size_t)node * 64))[q];
    float4 bb = ((const float4*)bias)[q];
    float4 r;
    r.x = fmaxf(dd * (acc.x + self.x) + bb.x, 0.0f);
    r.y = fmaxf(dd * (acc.y + self.y) + bb.y, 0.0f);
    r.z = fmaxf(dd * (acc.z + self.z) + bb.z, 0.0f);
    r.w = fmaxf(dd * (acc.w + self.w) + bb.w, 0.0f);
    if constexpr (HEAD) {
        float4 wq = ((const float4*)Wp)[q];
        float s = r.x * wq.x + r.y * wq.y + r.z * wq.z + r.w * wq.w;
#pragma unroll
        for (int m = 1; m <= 8; m <<= 1) s += __shfl_xor(s, m);
        if (lane == 0) out[node] = s + bp[0];
    } else {
        if (slot == 0)
            ((float4*)(out + (size_t)node * 64))[q] = r;
    }
}

extern "C" void kernel_launch(void* const* d_in, const int* in_sizes, int n_in,
                              void* d_out, int out_size, void* d_ws, size_t ws_size,
                              hipStream_t stream) {
    const float* x  = (const float*)d_in[0];
    const int*   ei = (const int*)d_in[1];
    const float* W1 = (const float*)d_in[2];
    const float* b1 = (const float*)d_in[3];
    const float* W2 = (const float*)d_in[4];
    const float* b2 = (const float*)d_in[5];
    const float* Wp = (const float*)d_in[6];
    const float* bp = (const float*)d_in[7];
    float* out = (float*)d_out;

    const int N = GNN_N, E = GNN_E;
    const int* srcv = ei;
    const int* dstv = ei + E;

    // workspace layout (bytes):
    //   hist   @ 0         : NBLK*NBUCK ints
    //   bbase  @ 400,896   : 392 ints
    //   rowptr @ 402,944   : N ints
    //   deg    @ 802,944   : N ints
    //   dis    @ 1,202,944 : N floats
    //   csr    @ 1,603,584 : E ints
    //   bufA   @ 8,003,584 : N*64 floats
    //   bufB   @ 33,603,584: N*64 floats
    //   part   @ 33,603,584: E u32 -- aliases bufB (part dead before bufB written)
    char* ws = (char*)d_ws;
    int*   hist   = (int*)(ws + 0);
    int*   bbase  = (int*)(ws + 400896);
    int*   rowptr = (int*)(ws + 402944);
    int*   deg    = (int*)(ws + 802944);
    float* dis    = (float*)(ws + 1202944);
    int*   csr    = (int*)(ws + 1603584);
    float* bufA   = (float*)(ws + 8003584);
    float* bufB   = (float*)(ws + 33603584);
    unsigned int* part = (unsigned int*)(ws + 33603584);

    // CSR build
    k_hist   <<<NBLK, 256, 0, stream>>>(dstv, hist);
    k_colscan<<<1, 512, 0, stream>>>(hist, bbase);
    k_part   <<<NBLK, 256, 0, stream>>>(srcv, dstv, hist, bbase, part);
    k_bsort  <<<NBUCK, 256, 0, stream>>>(part, bbase, csr, rowptr, deg, dis);

    // layer 1: bufA = (x@W1)*dis ; bufB = relu(...)
    k_mm64<<<(N + 63) / 64, 256, 0, stream>>>(x, W1, dis, bufA, N);
    k_gather4<false><<<(N + 3) / 4, 256, 0, stream>>>(bufA, csr, rowptr, deg, dis,
                                                      b1, nullptr, nullptr, bufB, N);
    // layer 2 + head: bufA = (bufB@W2)*dis ; out = head(relu(...))
    k_mm64<<<(N + 63) / 64, 256, 0, stream>>>(bufB, W2, dis, bufA, N);
    k_gather4<true><<<(N + 3) / 4, 256, 0, stream>>>(bufA, csr, rowptr, deg, dis,
                                                     b2, Wp, bp, out, N);
}

// Round 7
// 214.582 us; speedup vs baseline: 1.4013x; 1.0120x over previous
//
#include <hip/hip_runtime.h>

// BusStopGNN round 7:
//  - gather: 16 rows in flight per wave (4 chains x 4 slots) -- round-6 showed
//    latency/concurrency-bound (3.1 TB/s L2-fill, in-flight ~= need at 600ns).
//  - colscan replaced by tiled parallel transpose-scan (25 blocks) + 1-block
//    total-scan: old single-block version serialized 800KB on one CU.
//  - mm64 (rolled k-loop), counting-sort CSR build otherwise unchanged.

#define GNN_N 100000
#define GNN_E 1600000
#define NBUCK 391   // ceil(N/256), bucket = dst >> 8
#define NBLK  256
#define EPB   6250  // E / NBLK
#define SCTILE 16   // buckets per cscan block

// ---- Pass 1: per-block LDS histogram over dst buckets ----
__global__ __launch_bounds__(256) void k_hist(const int* __restrict__ dst,
                                              int* __restrict__ hist) {
    __shared__ int h[NBUCK];
    for (int i = threadIdx.x; i < NBUCK; i += 256) h[i] = 0;
    __syncthreads();
    int b = blockIdx.x;
    int e0 = b * EPB, e1 = min(e0 + EPB, GNN_E);
    for (int e = e0 + threadIdx.x; e < e1; e += 256)
        atomicAdd(&h[dst[e] >> 8], 1);
    __syncthreads();
    for (int i = threadIdx.x; i < NBUCK; i += 256)
        hist[b * NBUCK + i] = h[i];
}

// ---- Pass 2a: tiled column scan. Block handles 16 buckets (columns);
// thread b loads row b's 16 entries (coalesced per-thread 64B), waves do
// 16-lane segmented scans per column. hist[b][k] <- prefix_{b'<b}, tot[k]=sum.
__global__ __launch_bounds__(256) void k_cscan(int* __restrict__ hist,
                                               int* __restrict__ tot) {
    __shared__ int tile[256][SCTILE + 1];
    int k0 = blockIdx.x * SCTILE;
    int b = threadIdx.x;
#pragma unroll
    for (int i = 0; i < SCTILE; ++i) {
        int k = k0 + i;
        tile[b][i] = (k < NBUCK) ? hist[b * NBUCK + k] : 0;
    }
    __syncthreads();
    int lane = b & 63, w = b >> 6;
    int cSub = lane >> 4;          // which of my wave's 4 columns
    int l16 = lane & 15;           // position within 16-lane group
    int col = w * 4 + cSub;
    int run = 0;
    for (int chunk = 0; chunk < 16; ++chunk) {
        int idx = chunk * 16 + l16;
        int v = tile[idx][col];
        int s = v;
#pragma unroll
        for (int o = 1; o < 16; o <<= 1) {
            int t = __shfl_up(s, o);
            if (l16 >= o) s += t;  // guarded: stays within 16-group
        }
        tile[idx][col] = s - v + run;       // exclusive prefix
        run += __shfl(s, lane | 15);        // group total (lane l16=15)
    }
    if (l16 == 0 && k0 + col < NBUCK) tot[k0 + col] = run;
    __syncthreads();
#pragma unroll
    for (int i = 0; i < SCTILE; ++i) {
        int k = k0 + i;
        if (k < NBUCK) hist[b * NBUCK + k] = tile[b][i];
    }
}

// ---- Pass 2b: scan bucket totals -> bbase ----
__global__ __launch_bounds__(512) void k_btot(const int* __restrict__ tot,
                                              int* __restrict__ bbase) {
    __shared__ int s[NBUCK];
    int t = threadIdx.x;
    if (t < NBUCK) s[t] = tot[t];
    __syncthreads();
    if (t == 0) {
        int run = 0;
        for (int i = 0; i < NBUCK; ++i) { int v = s[i]; s[i] = run; run += v; }
    }
    __syncthreads();
    if (t < NBUCK) bbase[t] = s[t];
    if (t == 0) bbase[NBUCK] = GNN_E;
}

// ---- Pass 3: partition edges into bucket regions; pack (dst&255)<<17 | src ----
__global__ __launch_bounds__(256) void k_part(const int* __restrict__ src,
                                              const int* __restrict__ dst,
                                              const int* __restrict__ hist,
                                              const int* __restrict__ bbase,
                                              unsigned int* __restrict__ part) {
    __shared__ int off[NBUCK];
    int b = blockIdx.x;
    for (int i = threadIdx.x; i < NBUCK; i += 256)
        off[i] = bbase[i] + hist[b * NBUCK + i];
    __syncthreads();
    int e0 = b * EPB, e1 = min(e0 + EPB, GNN_E);
    for (int e = e0 + threadIdx.x; e < e1; e += 256) {
        int d = dst[e], s = src[e];
        int slot = atomicAdd(&off[d >> 8], 1);
        part[slot] = ((unsigned int)(d & 255) << 17) | (unsigned int)s;
    }
}

// ---- Pass 4: per-bucket counting sort -> csr, rowptr, deg, dis ----
__global__ __launch_bounds__(256) void k_bsort(const unsigned int* __restrict__ part,
                                               const int* __restrict__ bbase,
                                               int* __restrict__ csr,
                                               int* __restrict__ rowptr,
                                               int* __restrict__ deg,
                                               float* __restrict__ dis) {
    __shared__ int cnt[256];
    __shared__ int pos[256];
    int k = blockIdx.x;
    int t = threadIdx.x;
    cnt[t] = 0;
    __syncthreads();
    int e0 = bbase[k], e1 = bbase[k + 1];
    for (int e = e0 + t; e < e1; e += 256)
        atomicAdd(&cnt[part[e] >> 17], 1);
    __syncthreads();
    if (t == 0) {
        int run = 0;
        for (int i = 0; i < 256; ++i) { int c = cnt[i]; pos[i] = run; run += c; }
    }
    __syncthreads();
    int node = k * 256 + t;
    if (node < GNN_N) {
        rowptr[node] = e0 + pos[t];
        deg[node]    = cnt[t];
        dis[node]    = rsqrtf((float)cnt[t] + 1.0f);
    }
    __syncthreads();
    for (int e = e0 + t; e < e1; e += 256) {
        unsigned int p = part[e];
        int slot = e0 + atomicAdd(&pos[p >> 17], 1);
        csr[slot] = (int)(p & 0x1FFFF);
    }
}

// ---- tiled 64x64 matmul, dis epilogue: Y[row] = (X@W)[row]*dis[row] ----
__global__ __launch_bounds__(256) void k_mm64(const float* __restrict__ X,
                                              const float* __restrict__ W,
                                              const float* __restrict__ dis,
                                              float* __restrict__ Y, int n) {
    __shared__ float  Xs[64][68];
    __shared__ float4 Wsh[64 * 16];
    int tid = threadIdx.x;
    int base = blockIdx.x * 64;
    for (int i = tid; i < 1024; i += 256)
        Wsh[i] = ((const float4*)W)[i];
#pragma unroll
    for (int i = 0; i < 4; ++i) {
        int g = i * 256 + tid;
        int r = g >> 4, c4 = g & 15;
        int row = base + r;
        float4 v = (row < n) ? ((const float4*)(X + (size_t)row * 64))[c4]
                             : make_float4(0.f, 0.f, 0.f, 0.f);
        *(float4*)&Xs[r][c4 * 4] = v;
    }
    __syncthreads();
    int tj = tid & 15;
    int ti = tid >> 4;
    float4 a0 = {0,0,0,0}, a1 = {0,0,0,0}, a2 = {0,0,0,0}, a3 = {0,0,0,0};
#pragma unroll 1
    for (int k4 = 0; k4 < 16; ++k4) {
        float4 x0 = *(const float4*)&Xs[ti * 4 + 0][k4 * 4];
        float4 x1 = *(const float4*)&Xs[ti * 4 + 1][k4 * 4];
        float4 x2 = *(const float4*)&Xs[ti * 4 + 2][k4 * 4];
        float4 x3 = *(const float4*)&Xs[ti * 4 + 3][k4 * 4];
        float4 w0 = Wsh[(k4 * 4 + 0) * 16 + tj];
        float4 w1 = Wsh[(k4 * 4 + 1) * 16 + tj];
        float4 w2 = Wsh[(k4 * 4 + 2) * 16 + tj];
        float4 w3 = Wsh[(k4 * 4 + 3) * 16 + tj];
#define FMA4(A, XV)                                                      \
        A.x += XV.x * w0.x + XV.y * w1.x + XV.z * w2.x + XV.w * w3.x;    \
        A.y += XV.x * w0.y + XV.y * w1.y + XV.z * w2.y + XV.w * w3.y;    \
        A.z += XV.x * w0.z + XV.y * w1.z + XV.z * w2.z + XV.w * w3.z;    \
        A.w += XV.x * w0.w + XV.y * w1.w + XV.z * w2.w + XV.w * w3.w;
        FMA4(a0, x0) FMA4(a1, x1) FMA4(a2, x2) FMA4(a3, x3)
#undef FMA4
    }
#pragma unroll
    for (int q = 0; q < 4; ++q) {
        int row = base + ti * 4 + q;
        if (row < n) {
            float d = dis[row];
            float4 a = (q == 0) ? a0 : (q == 1) ? a1 : (q == 2) ? a2 : a3;
            a.x *= d; a.y *= d; a.z *= d; a.w *= d;
            ((float4*)(Y + (size_t)row * 64))[tj] = a;
        }
    }
}

// ---- gather: lane = (channel-quad q, edge-slot s); 16 rows in flight ----
template<bool HEAD>
__global__ __launch_bounds__(256) void k_gather4(
        const float* __restrict__ Hs, const int* __restrict__ csr,
        const int* __restrict__ rowptr, const int* __restrict__ deg,
        const float* __restrict__ dis, const float* __restrict__ bias,
        const float* __restrict__ Wp, const float* __restrict__ bp,
        float* __restrict__ out, int n) {
    int tid = threadIdx.x;
    int lane = tid & 63;
    int q = lane & 15;        // channel quad
    int slot = lane >> 4;     // edge slot 0..3
    int node = blockIdx.x * 4 + (tid >> 6);
    if (node >= n) return;
    int base = rowptr[node];
    int cnt  = deg[node];
    float dd = dis[node];
    float4 a0 = {0,0,0,0}, a1 = {0,0,0,0}, a2 = {0,0,0,0}, a3 = {0,0,0,0};
    int j = 0;
    for (; j + 16 <= cnt; j += 16) {   // 16 rows (4KB) in flight per wave
        int s0 = csr[base + j + slot];
        int s1 = csr[base + j + 4 + slot];
        int s2 = csr[base + j + 8 + slot];
        int s3 = csr[base + j + 12 + slot];
        float4 v0 = ((const float4*)(Hs + (size_t)s0 * 64))[q];
        float4 v1 = ((const float4*)(Hs + (size_t)s1 * 64))[q];
        float4 v2 = ((const float4*)(Hs + (size_t)s2 * 64))[q];
        float4 v3 = ((const float4*)(Hs + (size_t)s3 * 64))[q];
        a0.x += v0.x; a0.y += v0.y; a0.z += v0.z; a0.w += v0.w;
        a1.x += v1.x; a1.y += v1.y; a1.z += v1.z; a1.w += v1.w;
        a2.x += v2.x; a2.y += v2.y; a2.z += v2.z; a2.w += v2.w;
        a3.x += v3.x; a3.y += v3.y; a3.z += v3.z; a3.w += v3.w;
    }
    if (j + 8 <= cnt) {
        int s0 = csr[base + j + slot];
        int s1 = csr[base + j + 4 + slot];
        float4 v0 = ((const float4*)(Hs + (size_t)s0 * 64))[q];
        float4 v1 = ((const float4*)(Hs + (size_t)s1 * 64))[q];
        a0.x += v0.x; a0.y += v0.y; a0.z += v0.z; a0.w += v0.w;
        a1.x += v1.x; a1.y += v1.y; a1.z += v1.z; a1.w += v1.w;
        j += 8;
    }
    if (j + 4 <= cnt) {
        int s = csr[base + j + slot];
        float4 v = ((const float4*)(Hs + (size_t)s * 64))[q];
        a2.x += v.x; a2.y += v.y; a2.z += v.z; a2.w += v.w;
        j += 4;
    }
    int rem = cnt - j;               // 0..3 masked tail
    if (slot < rem) {
        int s = csr[base + j + slot];
        float4 v = ((const float4*)(Hs + (size_t)s * 64))[q];
        a3.x += v.x; a3.y += v.y; a3.z += v.z; a3.w += v.w;
    }
    float4 acc;
    acc.x = (a0.x + a1.x) + (a2.x + a3.x);
    acc.y = (a0.y + a1.y) + (a2.y + a3.y);
    acc.z = (a0.z + a1.z) + (a2.z + a3.z);
    acc.w = (a0.w + a1.w) + (a2.w + a3.w);
#pragma unroll
    for (int m = 16; m <= 32; m <<= 1) {   // combine 4 edge-slots
        acc.x += __shfl_xor(acc.x, m);
        acc.y += __shfl_xor(acc.y, m);
        acc.z += __shfl_xor(acc.z, m);
        acc.w += __shfl_xor(acc.w, m);
    }
    float4 self = ((const float4*)(Hs + (size_t)node * 64))[q];
    float4 bb = ((const float4*)bias)[q];
    float4 r;
    r.x = fmaxf(dd * (acc.x + self.x) + bb.x, 0.0f);
    r.y = fmaxf(dd * (acc.y + self.y) + bb.y, 0.0f);
    r.z = fmaxf(dd * (acc.z + self.z) + bb.z, 0.0f);
    r.w = fmaxf(dd * (acc.w + self.w) + bb.w, 0.0f);
    if constexpr (HEAD) {
        float4 wq = ((const float4*)Wp)[q];
        float s = r.x * wq.x + r.y * wq.y + r.z * wq.z + r.w * wq.w;
#pragma unroll
        for (int m = 1; m <= 8; m <<= 1) s += __shfl_xor(s, m);
        if (lane == 0) out[node] = s + bp[0];
    } else {
        if (slot == 0)
            ((float4*)(out + (size_t)node * 64))[q] = r;
    }
}

extern "C" void kernel_launch(void* const* d_in, const int* in_sizes, int n_in,
                              void* d_out, int out_size, void* d_ws, size_t ws_size,
                              hipStream_t stream) {
    const float* x  = (const float*)d_in[0];
    const int*   ei = (const int*)d_in[1];
    const float* W1 = (const float*)d_in[2];
    const float* b1 = (const float*)d_in[3];
    const float* W2 = (const float*)d_in[4];
    const float* b2 = (const float*)d_in[5];
    const float* Wp = (const float*)d_in[6];
    const float* bp = (const float*)d_in[7];
    float* out = (float*)d_out;

    const int N = GNN_N, E = GNN_E;
    const int* srcv = ei;
    const int* dstv = ei + E;

    // workspace layout (bytes) -- unchanged from round 6:
    //   hist   @ 0         : NBLK*NBUCK ints
    //   bbase  @ 400,896   : 392 ints
    //   rowptr @ 402,944   : N ints
    //   deg    @ 802,944   : N ints
    //   dis    @ 1,202,944 : N floats  (also hosts `tot` between cscan/btot;
    //                                   dis is written later, by k_bsort)
    //   csr    @ 1,603,584 : E ints
    //   bufA   @ 8,003,584 : N*64 floats
    //   bufB   @ 33,603,584: N*64 floats
    //   part   @ 33,603,584: E u32 -- aliases bufB (part dead before bufB written)
    char* ws = (char*)d_ws;
    int*   hist   = (int*)(ws + 0);
    int*   bbase  = (int*)(ws + 400896);
    int*   rowptr = (int*)(ws + 402944);
    int*   deg    = (int*)(ws + 802944);
    float* dis    = (float*)(ws + 1202944);
    int*   tot    = (int*)(ws + 1202944);   // aliases dis (dead until bsort)
    int*   csr    = (int*)(ws + 1603584);
    float* bufA   = (float*)(ws + 8003584);
    float* bufB   = (float*)(ws + 33603584);
    unsigned int* part = (unsigned int*)(ws + 33603584);

    // CSR build
    k_hist <<<NBLK, 256, 0, stream>>>(dstv, hist);
    k_cscan<<<(NBUCK + SCTILE - 1) / SCTILE, 256, 0, stream>>>(hist, tot);
    k_btot <<<1, 512, 0, stream>>>(tot, bbase);
    k_part <<<NBLK, 256, 0, stream>>>(srcv, dstv, hist, bbase, part);
    k_bsort<<<NBUCK, 256, 0, stream>>>(part, bbase, csr, rowptr, deg, dis);

    // layer 1
    k_mm64<<<(N + 63) / 64, 256, 0, stream>>>(x, W1, dis, bufA, N);
    k_gather4<false><<<(N + 3) / 4, 256, 0, stream>>>(bufA, csr, rowptr, deg, dis,
                                                      b1, nullptr, nullptr, bufB, N);
    // layer 2 + head
    k_mm64<<<(N + 63) / 64, 256, 0, stream>>>(bufB, W2, dis, bufA, N);
    k_gather4<true><<<(N + 3) / 4, 256, 0, stream>>>(bufA, csr, rowptr, deg, dis,
                                                     b2, Wp, bp, out, N);
}

// Round 8
// 178.858 us; speedup vs baseline: 1.6812x; 1.1997x over previous
//
#include <hip/hip_runtime.h>
#include <hip/hip_fp16.h>

// BusStopGNN round 8: fp16 gather tables.
// Round-7 A/B showed gather is at the L2-fill-rate floor (16-deep == 8-deep,
// 3.2 TB/s, FETCH pinned at 192 MB = 8 XCDs x full 25.6 MB table). Only lever
// left is bytes: mm64 writes T=(H@W)*dis as fp16 (12.8 MB), gather reads fp16
// and accumulates f32. Lane map: 8 channel-octets x 8 edge-slots.
// CSR build (counting sort) and rolled-k mm64 structure unchanged.

#define GNN_N 100000
#define GNN_E 1600000
#define NBUCK 391   // ceil(N/256), bucket = dst >> 8
#define NBLK  256
#define EPB   6250  // E / NBLK
#define SCTILE 16

// ---- Pass 1: per-block LDS histogram over dst buckets ----
__global__ __launch_bounds__(256) void k_hist(const int* __restrict__ dst,
                                              int* __restrict__ hist) {
    __shared__ int h[NBUCK];
    for (int i = threadIdx.x; i < NBUCK; i += 256) h[i] = 0;
    __syncthreads();
    int b = blockIdx.x;
    int e0 = b * EPB, e1 = min(e0 + EPB, GNN_E);
    for (int e = e0 + threadIdx.x; e < e1; e += 256)
        atomicAdd(&h[dst[e] >> 8], 1);
    __syncthreads();
    for (int i = threadIdx.x; i < NBUCK; i += 256)
        hist[b * NBUCK + i] = h[i];
}

// ---- Pass 2a: tiled column scan ----
__global__ __launch_bounds__(256) void k_cscan(int* __restrict__ hist,
                                               int* __restrict__ tot) {
    __shared__ int tile[256][SCTILE + 1];
    int k0 = blockIdx.x * SCTILE;
    int b = threadIdx.x;
#pragma unroll
    for (int i = 0; i < SCTILE; ++i) {
        int k = k0 + i;
        tile[b][i] = (k < NBUCK) ? hist[b * NBUCK + k] : 0;
    }
    __syncthreads();
    int lane = b & 63, w = b >> 6;
    int cSub = lane >> 4;
    int l16 = lane & 15;
    int col = w * 4 + cSub;
    int run = 0;
    for (int chunk = 0; chunk < 16; ++chunk) {
        int idx = chunk * 16 + l16;
        int v = tile[idx][col];
        int s = v;
#pragma unroll
        for (int o = 1; o < 16; o <<= 1) {
            int t = __shfl_up(s, o);
            if (l16 >= o) s += t;
        }
        tile[idx][col] = s - v + run;
        run += __shfl(s, lane | 15);
    }
    if (l16 == 0 && k0 + col < NBUCK) tot[k0 + col] = run;
    __syncthreads();
#pragma unroll
    for (int i = 0; i < SCTILE; ++i) {
        int k = k0 + i;
        if (k < NBUCK) hist[b * NBUCK + k] = tile[b][i];
    }
}

// ---- Pass 2b: scan bucket totals -> bbase ----
__global__ __launch_bounds__(512) void k_btot(const int* __restrict__ tot,
                                              int* __restrict__ bbase) {
    __shared__ int s[NBUCK];
    int t = threadIdx.x;
    if (t < NBUCK) s[t] = tot[t];
    __syncthreads();
    if (t == 0) {
        int run = 0;
        for (int i = 0; i < NBUCK; ++i) { int v = s[i]; s[i] = run; run += v; }
    }
    __syncthreads();
    if (t < NBUCK) bbase[t] = s[t];
    if (t == 0) bbase[NBUCK] = GNN_E;
}

// ---- Pass 3: partition edges; pack (dst&255)<<17 | src ----
__global__ __launch_bounds__(256) void k_part(const int* __restrict__ src,
                                              const int* __restrict__ dst,
                                              const int* __restrict__ hist,
                                              const int* __restrict__ bbase,
                                              unsigned int* __restrict__ part) {
    __shared__ int off[NBUCK];
    int b = blockIdx.x;
    for (int i = threadIdx.x; i < NBUCK; i += 256)
        off[i] = bbase[i] + hist[b * NBUCK + i];
    __syncthreads();
    int e0 = b * EPB, e1 = min(e0 + EPB, GNN_E);
    for (int e = e0 + threadIdx.x; e < e1; e += 256) {
        int d = dst[e], s = src[e];
        int slot = atomicAdd(&off[d >> 8], 1);
        part[slot] = ((unsigned int)(d & 255) << 17) | (unsigned int)s;
    }
}

// ---- Pass 4: per-bucket counting sort -> csr, rowptr, deg, dis ----
__global__ __launch_bounds__(256) void k_bsort(const unsigned int* __restrict__ part,
                                               const int* __restrict__ bbase,
                                               int* __restrict__ csr,
                                               int* __restrict__ rowptr,
                                               int* __restrict__ deg,
                                               float* __restrict__ dis) {
    __shared__ int cnt[256];
    __shared__ int pos[256];
    int k = blockIdx.x;
    int t = threadIdx.x;
    cnt[t] = 0;
    __syncthreads();
    int e0 = bbase[k], e1 = bbase[k + 1];
    for (int e = e0 + t; e < e1; e += 256)
        atomicAdd(&cnt[part[e] >> 17], 1);
    __syncthreads();
    if (t == 0) {
        int run = 0;
        for (int i = 0; i < 256; ++i) { int c = cnt[i]; pos[i] = run; run += c; }
    }
    __syncthreads();
    int node = k * 256 + t;
    if (node < GNN_N) {
        rowptr[node] = e0 + pos[t];
        deg[node]    = cnt[t];
        dis[node]    = rsqrtf((float)cnt[t] + 1.0f);
    }
    __syncthreads();
    for (int e = e0 + t; e < e1; e += 256) {
        unsigned int p = part[e];
        int slot = e0 + atomicAdd(&pos[p >> 17], 1);
        csr[slot] = (int)(p & 0x1FFFF);
    }
}

// ---- tiled 64x64 matmul, fp16 output: Y[row] = fp16((X@W)[row]*dis[row]) ----
__global__ __launch_bounds__(256) void k_mm64h(const float* __restrict__ X,
                                               const float* __restrict__ W,
                                               const float* __restrict__ dis,
                                               __half* __restrict__ Y, int n) {
    __shared__ float  Xs[64][68];
    __shared__ float4 Wsh[64 * 16];
    int tid = threadIdx.x;
    int base = blockIdx.x * 64;
    for (int i = tid; i < 1024; i += 256)
        Wsh[i] = ((const float4*)W)[i];
#pragma unroll
    for (int i = 0; i < 4; ++i) {
        int g = i * 256 + tid;
        int r = g >> 4, c4 = g & 15;
        int row = base + r;
        float4 v = (row < n) ? ((const float4*)(X + (size_t)row * 64))[c4]
                             : make_float4(0.f, 0.f, 0.f, 0.f);
        *(float4*)&Xs[r][c4 * 4] = v;
    }
    __syncthreads();
    int tj = tid & 15;
    int ti = tid >> 4;
    float4 a0 = {0,0,0,0}, a1 = {0,0,0,0}, a2 = {0,0,0,0}, a3 = {0,0,0,0};
#pragma unroll 1
    for (int k4 = 0; k4 < 16; ++k4) {
        float4 x0 = *(const float4*)&Xs[ti * 4 + 0][k4 * 4];
        float4 x1 = *(const float4*)&Xs[ti * 4 + 1][k4 * 4];
        float4 x2 = *(const float4*)&Xs[ti * 4 + 2][k4 * 4];
        float4 x3 = *(const float4*)&Xs[ti * 4 + 3][k4 * 4];
        float4 w0 = Wsh[(k4 * 4 + 0) * 16 + tj];
        float4 w1 = Wsh[(k4 * 4 + 1) * 16 + tj];
        float4 w2 = Wsh[(k4 * 4 + 2) * 16 + tj];
        float4 w3 = Wsh[(k4 * 4 + 3) * 16 + tj];
#define FMA4(A, XV)                                                      \
        A.x += XV.x * w0.x + XV.y * w1.x + XV.z * w2.x + XV.w * w3.x;    \
        A.y += XV.x * w0.y + XV.y * w1.y + XV.z * w2.y + XV.w * w3.y;    \
        A.z += XV.x * w0.z + XV.y * w1.z + XV.z * w2.z + XV.w * w3.z;    \
        A.w += XV.x * w0.w + XV.y * w1.w + XV.z * w2.w + XV.w * w3.w;
        FMA4(a0, x0) FMA4(a1, x1) FMA4(a2, x2) FMA4(a3, x3)
#undef FMA4
    }
#pragma unroll
    for (int q = 0; q < 4; ++q) {
        int row = base + ti * 4 + q;
        if (row < n) {
            float d = dis[row];
            float4 a = (q == 0) ? a0 : (q == 1) ? a1 : (q == 2) ? a2 : a3;
            __half2 p0 = __floats2half2_rn(a.x * d, a.y * d);
            __half2 p1 = __floats2half2_rn(a.z * d, a.w * d);
            __half2* yp = (__half2*)(Y + (size_t)row * 64);
            yp[tj * 2 + 0] = p0;
            yp[tj * 2 + 1] = p1;
        }
    }
}

// ---- gather (fp16 table): lane = (channel-octet q, edge-slot s), 8 slots ----
// 8 lanes/row x 16B -> full 128B fp16 row coalesced; 16 rows in flight.
// out = relu( dis*(sum + self) + b ); HEAD adds fused Wp reduction.
#define ACC8(A, U) {                                                     \
    float2 f_;                                                           \
    f_ = __half22float2(*(__half2*)&U.x); A[0] += f_.x; A[1] += f_.y;    \
    f_ = __half22float2(*(__half2*)&U.y); A[2] += f_.x; A[3] += f_.y;    \
    f_ = __half22float2(*(__half2*)&U.z); A[4] += f_.x; A[5] += f_.y;    \
    f_ = __half22float2(*(__half2*)&U.w); A[6] += f_.x; A[7] += f_.y; }

template<bool HEAD>
__global__ __launch_bounds__(256) void k_gather8(
        const __half* __restrict__ T, const int* __restrict__ csr,
        const int* __restrict__ rowptr, const int* __restrict__ deg,
        const float* __restrict__ dis, const float* __restrict__ bias,
        const float* __restrict__ Wp, const float* __restrict__ bp,
        float* __restrict__ out, int n) {
    int tid = threadIdx.x;
    int lane = tid & 63;
    int q = lane & 7;         // channel octet: channels q*8 .. q*8+7
    int slot = lane >> 3;     // edge slot 0..7
    int node = blockIdx.x * 4 + (tid >> 6);
    if (node >= n) return;
    int base = rowptr[node];
    int cnt  = deg[node];
    float dd = dis[node];
    float a0[8], a1[8];
#pragma unroll
    for (int i = 0; i < 8; ++i) { a0[i] = 0.f; a1[i] = 0.f; }
    int j = 0;
    for (; j + 16 <= cnt; j += 16) {      // 16 rows (2KB fp16) in flight
        int s0 = csr[base + j + slot];
        int s1 = csr[base + j + 8 + slot];
        uint4 u0 = *(const uint4*)(T + (size_t)s0 * 64 + q * 8);
        uint4 u1 = *(const uint4*)(T + (size_t)s1 * 64 + q * 8);
        ACC8(a0, u0)
        ACC8(a1, u1)
    }
    if (j + 8 <= cnt) {
        int s = csr[base + j + slot];
        uint4 u = *(const uint4*)(T + (size_t)s * 64 + q * 8);
        ACC8(a0, u)
        j += 8;
    }
    int rem = cnt - j;                    // 0..7 masked tail
    if (slot < rem) {
        int s = csr[base + j + slot];
        uint4 u = *(const uint4*)(T + (size_t)s * 64 + q * 8);
        ACC8(a1, u)
    }
    float acc[8];
#pragma unroll
    for (int i = 0; i < 8; ++i) acc[i] = a0[i] + a1[i];
#pragma unroll
    for (int m = 8; m <= 32; m <<= 1) {   // combine 8 edge-slots
#pragma unroll
        for (int i = 0; i < 8; ++i) acc[i] += __shfl_xor(acc[i], m);
    }
    uint4 us = *(const uint4*)(T + (size_t)node * 64 + q * 8);
    float self[8];
#pragma unroll
    for (int i = 0; i < 8; ++i) self[i] = 0.f;
    ACC8(self, us)
    float4 bb0 = ((const float4*)bias)[q * 2 + 0];
    float4 bb1 = ((const float4*)bias)[q * 2 + 1];
    float r[8];
    r[0] = fmaxf(dd * (acc[0] + self[0]) + bb0.x, 0.f);
    r[1] = fmaxf(dd * (acc[1] + self[1]) + bb0.y, 0.f);
    r[2] = fmaxf(dd * (acc[2] + self[2]) + bb0.z, 0.f);
    r[3] = fmaxf(dd * (acc[3] + self[3]) + bb0.w, 0.f);
    r[4] = fmaxf(dd * (acc[4] + self[4]) + bb1.x, 0.f);
    r[5] = fmaxf(dd * (acc[5] + self[5]) + bb1.y, 0.f);
    r[6] = fmaxf(dd * (acc[6] + self[6]) + bb1.z, 0.f);
    r[7] = fmaxf(dd * (acc[7] + self[7]) + bb1.w, 0.f);
    if constexpr (HEAD) {
        float4 w0 = ((const float4*)Wp)[q * 2 + 0];
        float4 w1 = ((const float4*)Wp)[q * 2 + 1];
        float s = r[0] * w0.x + r[1] * w0.y + r[2] * w0.z + r[3] * w0.w
                + r[4] * w1.x + r[5] * w1.y + r[6] * w1.z + r[7] * w1.w;
#pragma unroll
        for (int m = 1; m <= 4; m <<= 1) s += __shfl_xor(s, m);
        if (lane == 0) out[node] = s + bp[0];
    } else {
        if (slot == 0) {
            float4* op = (float4*)(out + (size_t)node * 64 + q * 8);
            op[0] = make_float4(r[0], r[1], r[2], r[3]);
            op[1] = make_float4(r[4], r[5], r[6], r[7]);
        }
    }
}

extern "C" void kernel_launch(void* const* d_in, const int* in_sizes, int n_in,
                              void* d_out, int out_size, void* d_ws, size_t ws_size,
                              hipStream_t stream) {
    const float* x  = (const float*)d_in[0];
    const int*   ei = (const int*)d_in[1];
    const float* W1 = (const float*)d_in[2];
    const float* b1 = (const float*)d_in[3];
    const float* W2 = (const float*)d_in[4];
    const float* b2 = (const float*)d_in[5];
    const float* Wp = (const float*)d_in[6];
    const float* bp = (const float*)d_in[7];
    float* out = (float*)d_out;

    const int N = GNN_N, E = GNN_E;
    const int* srcv = ei;
    const int* dstv = ei + E;

    // workspace layout (bytes), total footprint 59.2 MB (same as round 7):
    //   hist @ 0           : NBLK*NBUCK ints
    //   bbase @ 400,896    : 392 ints
    //   rowptr @ 402,944   : N ints
    //   deg @ 802,944      : N ints
    //   dis/tot @ 1,202,944: N floats (tot aliases dis; dis written by bsort)
    //   csr @ 1,603,584    : E ints (6.4 MB)
    //   TA  @ 8,003,584    : N*64 fp16 (12.8 MB) -- layer-1 table
    //   h1  @ 20,803,584   : N*64 f32 (25.6 MB)  -- gather-1 output
    //   TB  @ 46,403,584   : N*64 fp16 (12.8 MB) -- layer-2 table
    //   part @ 46,403,584  : E u32 (6.4 MB) -- aliases TB (part dead after
    //                        bsort, long before mm64h-2 writes TB)
    char* ws = (char*)d_ws;
    int*    hist   = (int*)(ws + 0);
    int*    bbase  = (int*)(ws + 400896);
    int*    rowptr = (int*)(ws + 402944);
    int*    deg    = (int*)(ws + 802944);
    float*  dis    = (float*)(ws + 1202944);
    int*    tot    = (int*)(ws + 1202944);
    int*    csr    = (int*)(ws + 1603584);
    __half* TA     = (__half*)(ws + 8003584);
    float*  h1     = (float*)(ws + 20803584);
    __half* TB     = (__half*)(ws + 46403584);
    unsigned int* part = (unsigned int*)(ws + 46403584);

    // CSR build
    k_hist <<<NBLK, 256, 0, stream>>>(dstv, hist);
    k_cscan<<<(NBUCK + SCTILE - 1) / SCTILE, 256, 0, stream>>>(hist, tot);
    k_btot <<<1, 512, 0, stream>>>(tot, bbase);
    k_part <<<NBLK, 256, 0, stream>>>(srcv, dstv, hist, bbase, part);
    k_bsort<<<NBUCK, 256, 0, stream>>>(part, bbase, csr, rowptr, deg, dis);

    // layer 1: TA = fp16((x@W1)*dis) ; h1 = relu(gather)
    k_mm64h<<<(N + 63) / 64, 256, 0, stream>>>(x, W1, dis, TA, N);
    k_gather8<false><<<(N + 3) / 4, 256, 0, stream>>>(TA, csr, rowptr, deg, dis,
                                                      b1, nullptr, nullptr, h1, N);
    // layer 2 + head: TB = fp16((h1@W2)*dis) ; out = head(relu(gather))
    k_mm64h<<<(N + 63) / 64, 256, 0, stream>>>(h1, W2, dis, TB, N);
    k_gather8<true><<<(N + 3) / 4, 256, 0, stream>>>(TB, csr, rowptr, deg, dis,
                                                     b2, Wp, bp, out, N);
}

// Round 9
// 155.180 us; speedup vs baseline: 1.9377x; 1.1526x over previous
//
#include <hip/hip_runtime.h>
#include <hip/hip_fp16.h>

// BusStopGNN round 9: gather restructured as 8-lane-group-per-node.
// Round-8 counters: gather8 VALUBusy 67%, fill 1.85 TB/s << 3.2 floor ->
// per-node overhead-bound (wave-per-node + 24-shfl reduction amortized over
// deg~16). New mapping: wave = 8 nodes x 8 lanes; each lane accumulates its
// 8 channels across the node's edges in registers -- no aggregation shuffle.
// fp16 tables, counting-sort CSR build, rolled-k mm64h unchanged.

#define GNN_N 100000
#define GNN_E 1600000
#define NBUCK 391   // ceil(N/256), bucket = dst >> 8
#define NBLK  256
#define EPB   6250  // E / NBLK
#define SCTILE 16

// ---- Pass 1: per-block LDS histogram over dst buckets ----
__global__ __launch_bounds__(256) void k_hist(const int* __restrict__ dst,
                                              int* __restrict__ hist) {
    __shared__ int h[NBUCK];
    for (int i = threadIdx.x; i < NBUCK; i += 256) h[i] = 0;
    __syncthreads();
    int b = blockIdx.x;
    int e0 = b * EPB, e1 = min(e0 + EPB, GNN_E);
    for (int e = e0 + threadIdx.x; e < e1; e += 256)
        atomicAdd(&h[dst[e] >> 8], 1);
    __syncthreads();
    for (int i = threadIdx.x; i < NBUCK; i += 256)
        hist[b * NBUCK + i] = h[i];
}

// ---- Pass 2a: tiled column scan ----
__global__ __launch_bounds__(256) void k_cscan(int* __restrict__ hist,
                                               int* __restrict__ tot) {
    __shared__ int tile[256][SCTILE + 1];
    int k0 = blockIdx.x * SCTILE;
    int b = threadIdx.x;
#pragma unroll
    for (int i = 0; i < SCTILE; ++i) {
        int k = k0 + i;
        tile[b][i] = (k < NBUCK) ? hist[b * NBUCK + k] : 0;
    }
    __syncthreads();
    int lane = b & 63, w = b >> 6;
    int cSub = lane >> 4;
    int l16 = lane & 15;
    int col = w * 4 + cSub;
    int run = 0;
    for (int chunk = 0; chunk < 16; ++chunk) {
        int idx = chunk * 16 + l16;
        int v = tile[idx][col];
        int s = v;
#pragma unroll
        for (int o = 1; o < 16; o <<= 1) {
            int t = __shfl_up(s, o);
            if (l16 >= o) s += t;
        }
        tile[idx][col] = s - v + run;
        run += __shfl(s, lane | 15);
    }
    if (l16 == 0 && k0 + col < NBUCK) tot[k0 + col] = run;
    __syncthreads();
#pragma unroll
    for (int i = 0; i < SCTILE; ++i) {
        int k = k0 + i;
        if (k < NBUCK) hist[b * NBUCK + k] = tile[b][i];
    }
}

// ---- Pass 2b: scan bucket totals -> bbase ----
__global__ __launch_bounds__(512) void k_btot(const int* __restrict__ tot,
                                              int* __restrict__ bbase) {
    __shared__ int s[NBUCK];
    int t = threadIdx.x;
    if (t < NBUCK) s[t] = tot[t];
    __syncthreads();
    if (t == 0) {
        int run = 0;
        for (int i = 0; i < NBUCK; ++i) { int v = s[i]; s[i] = run; run += v; }
    }
    __syncthreads();
    if (t < NBUCK) bbase[t] = s[t];
    if (t == 0) bbase[NBUCK] = GNN_E;
}

// ---- Pass 3: partition edges; pack (dst&255)<<17 | src ----
__global__ __launch_bounds__(256) void k_part(const int* __restrict__ src,
                                              const int* __restrict__ dst,
                                              const int* __restrict__ hist,
                                              const int* __restrict__ bbase,
                                              unsigned int* __restrict__ part) {
    __shared__ int off[NBUCK];
    int b = blockIdx.x;
    for (int i = threadIdx.x; i < NBUCK; i += 256)
        off[i] = bbase[i] + hist[b * NBUCK + i];
    __syncthreads();
    int e0 = b * EPB, e1 = min(e0 + EPB, GNN_E);
    for (int e = e0 + threadIdx.x; e < e1; e += 256) {
        int d = dst[e], s = src[e];
        int slot = atomicAdd(&off[d >> 8], 1);
        part[slot] = ((unsigned int)(d & 255) << 17) | (unsigned int)s;
    }
}

// ---- Pass 4: per-bucket counting sort -> csr, rowptr, deg, dis ----
__global__ __launch_bounds__(256) void k_bsort(const unsigned int* __restrict__ part,
                                               const int* __restrict__ bbase,
                                               int* __restrict__ csr,
                                               int* __restrict__ rowptr,
                                               int* __restrict__ deg,
                                               float* __restrict__ dis) {
    __shared__ int cnt[256];
    __shared__ int pos[256];
    int k = blockIdx.x;
    int t = threadIdx.x;
    cnt[t] = 0;
    __syncthreads();
    int e0 = bbase[k], e1 = bbase[k + 1];
    for (int e = e0 + t; e < e1; e += 256)
        atomicAdd(&cnt[part[e] >> 17], 1);
    __syncthreads();
    if (t == 0) {
        int run = 0;
        for (int i = 0; i < 256; ++i) { int c = cnt[i]; pos[i] = run; run += c; }
    }
    __syncthreads();
    int node = k * 256 + t;
    if (node < GNN_N) {
        rowptr[node] = e0 + pos[t];
        deg[node]    = cnt[t];
        dis[node]    = rsqrtf((float)cnt[t] + 1.0f);
    }
    __syncthreads();
    for (int e = e0 + t; e < e1; e += 256) {
        unsigned int p = part[e];
        int slot = e0 + atomicAdd(&pos[p >> 17], 1);
        csr[slot] = (int)(p & 0x1FFFF);
    }
}

// ---- tiled 64x64 matmul, fp16 output: Y[row] = fp16((X@W)[row]*dis[row]) ----
__global__ __launch_bounds__(256) void k_mm64h(const float* __restrict__ X,
                                               const float* __restrict__ W,
                                               const float* __restrict__ dis,
                                               __half* __restrict__ Y, int n) {
    __shared__ float  Xs[64][68];
    __shared__ float4 Wsh[64 * 16];
    int tid = threadIdx.x;
    int base = blockIdx.x * 64;
    for (int i = tid; i < 1024; i += 256)
        Wsh[i] = ((const float4*)W)[i];
#pragma unroll
    for (int i = 0; i < 4; ++i) {
        int g = i * 256 + tid;
        int r = g >> 4, c4 = g & 15;
        int row = base + r;
        float4 v = (row < n) ? ((const float4*)(X + (size_t)row * 64))[c4]
                             : make_float4(0.f, 0.f, 0.f, 0.f);
        *(float4*)&Xs[r][c4 * 4] = v;
    }
    __syncthreads();
    int tj = tid & 15;
    int ti = tid >> 4;
    float4 a0 = {0,0,0,0}, a1 = {0,0,0,0}, a2 = {0,0,0,0}, a3 = {0,0,0,0};
#pragma unroll 1
    for (int k4 = 0; k4 < 16; ++k4) {
        float4 x0 = *(const float4*)&Xs[ti * 4 + 0][k4 * 4];
        float4 x1 = *(const float4*)&Xs[ti * 4 + 1][k4 * 4];
        float4 x2 = *(const float4*)&Xs[ti * 4 + 2][k4 * 4];
        float4 x3 = *(const float4*)&Xs[ti * 4 + 3][k4 * 4];
        float4 w0 = Wsh[(k4 * 4 + 0) * 16 + tj];
        float4 w1 = Wsh[(k4 * 4 + 1) * 16 + tj];
        float4 w2 = Wsh[(k4 * 4 + 2) * 16 + tj];
        float4 w3 = Wsh[(k4 * 4 + 3) * 16 + tj];
#define FMA4(A, XV)                                                      \
        A.x += XV.x * w0.x + XV.y * w1.x + XV.z * w2.x + XV.w * w3.x;    \
        A.y += XV.x * w0.y + XV.y * w1.y + XV.z * w2.y + XV.w * w3.y;    \
        A.z += XV.x * w0.z + XV.y * w1.z + XV.z * w2.z + XV.w * w3.z;    \
        A.w += XV.x * w0.w + XV.y * w1.w + XV.z * w2.w + XV.w * w3.w;
        FMA4(a0, x0) FMA4(a1, x1) FMA4(a2, x2) FMA4(a3, x3)
#undef FMA4
    }
#pragma unroll
    for (int q = 0; q < 4; ++q) {
        int row = base + ti * 4 + q;
        if (row < n) {
            float d = dis[row];
            float4 a = (q == 0) ? a0 : (q == 1) ? a1 : (q == 2) ? a2 : a3;
            __half2 p0 = __floats2half2_rn(a.x * d, a.y * d);
            __half2 p1 = __floats2half2_rn(a.z * d, a.w * d);
            __half2* yp = (__half2*)(Y + (size_t)row * 64);
            yp[tj * 2 + 0] = p0;
            yp[tj * 2 + 1] = p1;
        }
    }
}

// ---- gather, group-per-node: wave = 8 nodes x 8 lanes ----
// Lane q of a group owns channels q*8..q*8+7 (16B of the fp16 row) and
// accumulates them across ALL of the node's edges -> no cross-lane combine.
#define ACC8(A, U) {                                                     \
    float2 f_;                                                           \
    f_ = __half22float2(*(__half2*)&U.x); A[0] += f_.x; A[1] += f_.y;    \
    f_ = __half22float2(*(__half2*)&U.y); A[2] += f_.x; A[3] += f_.y;    \
    f_ = __half22float2(*(__half2*)&U.z); A[4] += f_.x; A[5] += f_.y;    \
    f_ = __half22float2(*(__half2*)&U.w); A[6] += f_.x; A[7] += f_.y; }

template<bool HEAD>
__global__ __launch_bounds__(256) void k_gatherg(
        const __half* __restrict__ T, const int* __restrict__ csr,
        const int* __restrict__ rowptr, const int* __restrict__ deg,
        const float* __restrict__ dis, const float* __restrict__ bias,
        const float* __restrict__ Wp, const float* __restrict__ bp,
        float* __restrict__ out, int n) {
    int tid = threadIdx.x;
    int q = tid & 7;                       // channel octet within group
    int node = blockIdx.x * 32 + (tid >> 3);
    if (node >= n) return;
    int base = rowptr[node];
    int cnt  = deg[node];
    float dd = dis[node];
    const char* Tq = (const char*)T + q * 16;   // + s*128 per row
    float a0[8], a1[8];
#pragma unroll
    for (int i = 0; i < 8; ++i) { a0[i] = 0.f; a1[i] = 0.f; }
    int j = 0;
    for (; j + 4 <= cnt; j += 4) {          // 4 rows in flight per group
        int s0 = csr[base + j + 0];
        int s1 = csr[base + j + 1];
        int s2 = csr[base + j + 2];
        int s3 = csr[base + j + 3];
        uint4 u0 = *(const uint4*)(Tq + (size_t)s0 * 128);
        uint4 u1 = *(const uint4*)(Tq + (size_t)s1 * 128);
        uint4 u2 = *(const uint4*)(Tq + (size_t)s2 * 128);
        uint4 u3 = *(const uint4*)(Tq + (size_t)s3 * 128);
        ACC8(a0, u0)
        ACC8(a1, u1)
        ACC8(a0, u2)
        ACC8(a1, u3)
    }
    if (j + 2 <= cnt) {
        int s0 = csr[base + j + 0];
        int s1 = csr[base + j + 1];
        uint4 u0 = *(const uint4*)(Tq + (size_t)s0 * 128);
        uint4 u1 = *(const uint4*)(Tq + (size_t)s1 * 128);
        ACC8(a0, u0)
        ACC8(a1, u1)
        j += 2;
    }
    if (j < cnt) {
        int s = csr[base + j];
        uint4 u = *(const uint4*)(Tq + (size_t)s * 128);
        ACC8(a0, u)
    }
    // self row
    uint4 us = *(const uint4*)(Tq + (size_t)node * 128);
    ACC8(a1, us)
    float4 bb0 = ((const float4*)bias)[q * 2 + 0];
    float4 bb1 = ((const float4*)bias)[q * 2 + 1];
    float r[8];
    r[0] = fmaxf(dd * (a0[0] + a1[0]) + bb0.x, 0.f);
    r[1] = fmaxf(dd * (a0[1] + a1[1]) + bb0.y, 0.f);
    r[2] = fmaxf(dd * (a0[2] + a1[2]) + bb0.z, 0.f);
    r[3] = fmaxf(dd * (a0[3] + a1[3]) + bb0.w, 0.f);
    r[4] = fmaxf(dd * (a0[4] + a1[4]) + bb1.x, 0.f);
    r[5] = fmaxf(dd * (a0[5] + a1[5]) + bb1.y, 0.f);
    r[6] = fmaxf(dd * (a0[6] + a1[6]) + bb1.z, 0.f);
    r[7] = fmaxf(dd * (a0[7] + a1[7]) + bb1.w, 0.f);
    if constexpr (HEAD) {
        float4 w0 = ((const float4*)Wp)[q * 2 + 0];
        float4 w1 = ((const float4*)Wp)[q * 2 + 1];
        float s = r[0] * w0.x + r[1] * w0.y + r[2] * w0.z + r[3] * w0.w
                + r[4] * w1.x + r[5] * w1.y + r[6] * w1.z + r[7] * w1.w;
#pragma unroll
        for (int m = 1; m <= 4; m <<= 1) s += __shfl_xor(s, m);
        if (q == 0) out[node] = s + bp[0];
    } else {
        float4* op = (float4*)(out + (size_t)node * 64 + q * 8);
        op[0] = make_float4(r[0], r[1], r[2], r[3]);
        op[1] = make_float4(r[4], r[5], r[6], r[7]);
    }
}

extern "C" void kernel_launch(void* const* d_in, const int* in_sizes, int n_in,
                              void* d_out, int out_size, void* d_ws, size_t ws_size,
                              hipStream_t stream) {
    const float* x  = (const float*)d_in[0];
    const int*   ei = (const int*)d_in[1];
    const float* W1 = (const float*)d_in[2];
    const float* b1 = (const float*)d_in[3];
    const float* W2 = (const float*)d_in[4];
    const float* b2 = (const float*)d_in[5];
    const float* Wp = (const float*)d_in[6];
    const float* bp = (const float*)d_in[7];
    float* out = (float*)d_out;

    const int N = GNN_N, E = GNN_E;
    const int* srcv = ei;
    const int* dstv = ei + E;

    // workspace layout (bytes) -- unchanged from round 8:
    //   hist @ 0           : NBLK*NBUCK ints
    //   bbase @ 400,896    : 392 ints
    //   rowptr @ 402,944   : N ints
    //   deg @ 802,944      : N ints
    //   dis/tot @ 1,202,944: N floats (tot aliases dis; dis written by bsort)
    //   csr @ 1,603,584    : E ints (6.4 MB)
    //   TA  @ 8,003,584    : N*64 fp16 (12.8 MB)
    //   h1  @ 20,803,584   : N*64 f32 (25.6 MB)
    //   TB  @ 46,403,584   : N*64 fp16 (12.8 MB)
    //   part @ 46,403,584  : E u32 -- aliases TB (part dead after bsort)
    char* ws = (char*)d_ws;
    int*    hist   = (int*)(ws + 0);
    int*    bbase  = (int*)(ws + 400896);
    int*    rowptr = (int*)(ws + 402944);
    int*    deg    = (int*)(ws + 802944);
    float*  dis    = (float*)(ws + 1202944);
    int*    tot    = (int*)(ws + 1202944);
    int*    csr    = (int*)(ws + 1603584);
    __half* TA     = (__half*)(ws + 8003584);
    float*  h1     = (float*)(ws + 20803584);
    __half* TB     = (__half*)(ws + 46403584);
    unsigned int* part = (unsigned int*)(ws + 46403584);

    // CSR build
    k_hist <<<NBLK, 256, 0, stream>>>(dstv, hist);
    k_cscan<<<(NBUCK + SCTILE - 1) / SCTILE, 256, 0, stream>>>(hist, tot);
    k_btot <<<1, 512, 0, stream>>>(tot, bbase);
    k_part <<<NBLK, 256, 0, stream>>>(srcv, dstv, hist, bbase, part);
    k_bsort<<<NBUCK, 256, 0, stream>>>(part, bbase, csr, rowptr, deg, dis);

    // layer 1: TA = fp16((x@W1)*dis) ; h1 = relu(gather)
    k_mm64h<<<(N + 63) / 64, 256, 0, stream>>>(x, W1, dis, TA, N);
    k_gatherg<false><<<(N + 31) / 32, 256, 0, stream>>>(TA, csr, rowptr, deg, dis,
                                                        b1, nullptr, nullptr, h1, N);
    // layer 2 + head: TB = fp16((h1@W2)*dis) ; out = head(relu(gather))
    k_mm64h<<<(N + 63) / 64, 256, 0, stream>>>(h1, W2, dis, TB, N);
    k_gatherg<true><<<(N + 31) / 32, 256, 0, stream>>>(TB, csr, rowptr, deg, dis,
                                                       b2, Wp, bp, out, N);
}

// Round 10
// 152.729 us; speedup vs baseline: 1.9689x; 1.0161x over previous
//
#include <hip/hip_runtime.h>
#include <hip/hip_fp16.h>

// BusStopGNN round 10:
//  - h1 intermediate stored fp16 (gather-1 writes fp16, mm64h-2 reads fp16):
//    removes ~50 MB of streaming traffic.
//  - csr[] stores BYTE offsets (src*128) -> no per-load shift/mul in gather.
//  - mm64h templated on input type; LDS staging converts to f32 so the
//    rolled-k inner loop (no VGPR blowup) is unchanged.
// Group-per-node gather (wave = 8 nodes x 8 lanes), counting-sort CSR build.

#define GNN_N 100000
#define GNN_E 1600000
#define NBUCK 391   // ceil(N/256), bucket = dst >> 8
#define NBLK  256
#define EPB   6250  // E / NBLK
#define SCTILE 16

// ---- Pass 1: per-block LDS histogram over dst buckets ----
__global__ __launch_bounds__(256) void k_hist(const int* __restrict__ dst,
                                              int* __restrict__ hist) {
    __shared__ int h[NBUCK];
    for (int i = threadIdx.x; i < NBUCK; i += 256) h[i] = 0;
    __syncthreads();
    int b = blockIdx.x;
    int e0 = b * EPB, e1 = min(e0 + EPB, GNN_E);
    for (int e = e0 + threadIdx.x; e < e1; e += 256)
        atomicAdd(&h[dst[e] >> 8], 1);
    __syncthreads();
    for (int i = threadIdx.x; i < NBUCK; i += 256)
        hist[b * NBUCK + i] = h[i];
}

// ---- Pass 2a: tiled column scan ----
__global__ __launch_bounds__(256) void k_cscan(int* __restrict__ hist,
                                               int* __restrict__ tot) {
    __shared__ int tile[256][SCTILE + 1];
    int k0 = blockIdx.x * SCTILE;
    int b = threadIdx.x;
#pragma unroll
    for (int i = 0; i < SCTILE; ++i) {
        int k = k0 + i;
        tile[b][i] = (k < NBUCK) ? hist[b * NBUCK + k] : 0;
    }
    __syncthreads();
    int lane = b & 63, w = b >> 6;
    int cSub = lane >> 4;
    int l16 = lane & 15;
    int col = w * 4 + cSub;
    int run = 0;
    for (int chunk = 0; chunk < 16; ++chunk) {
        int idx = chunk * 16 + l16;
        int v = tile[idx][col];
        int s = v;
#pragma unroll
        for (int o = 1; o < 16; o <<= 1) {
            int t = __shfl_up(s, o);
            if (l16 >= o) s += t;
        }
        tile[idx][col] = s - v + run;
        run += __shfl(s, lane | 15);
    }
    if (l16 == 0 && k0 + col < NBUCK) tot[k0 + col] = run;
    __syncthreads();
#pragma unroll
    for (int i = 0; i < SCTILE; ++i) {
        int k = k0 + i;
        if (k < NBUCK) hist[b * NBUCK + k] = tile[b][i];
    }
}

// ---- Pass 2b: scan bucket totals -> bbase ----
__global__ __launch_bounds__(512) void k_btot(const int* __restrict__ tot,
                                              int* __restrict__ bbase) {
    __shared__ int s[NBUCK];
    int t = threadIdx.x;
    if (t < NBUCK) s[t] = tot[t];
    __syncthreads();
    if (t == 0) {
        int run = 0;
        for (int i = 0; i < NBUCK; ++i) { int v = s[i]; s[i] = run; run += v; }
    }
    __syncthreads();
    if (t < NBUCK) bbase[t] = s[t];
    if (t == 0) bbase[NBUCK] = GNN_E;
}

// ---- Pass 3: partition edges; pack (dst&255)<<17 | src ----
__global__ __launch_bounds__(256) void k_part(const int* __restrict__ src,
                                              const int* __restrict__ dst,
                                              const int* __restrict__ hist,
                                              const int* __restrict__ bbase,
                                              unsigned int* __restrict__ part) {
    __shared__ int off[NBUCK];
    int b = blockIdx.x;
    for (int i = threadIdx.x; i < NBUCK; i += 256)
        off[i] = bbase[i] + hist[b * NBUCK + i];
    __syncthreads();
    int e0 = b * EPB, e1 = min(e0 + EPB, GNN_E);
    for (int e = e0 + threadIdx.x; e < e1; e += 256) {
        int d = dst[e], s = src[e];
        int slot = atomicAdd(&off[d >> 8], 1);
        part[slot] = ((unsigned int)(d & 255) << 17) | (unsigned int)s;
    }
}

// ---- Pass 4: per-bucket counting sort -> csr (BYTE offsets), rowptr, deg, dis ----
__global__ __launch_bounds__(256) void k_bsort(const unsigned int* __restrict__ part,
                                               const int* __restrict__ bbase,
                                               int* __restrict__ csr,
                                               int* __restrict__ rowptr,
                                               int* __restrict__ deg,
                                               float* __restrict__ dis) {
    __shared__ int cnt[256];
    __shared__ int pos[256];
    int k = blockIdx.x;
    int t = threadIdx.x;
    cnt[t] = 0;
    __syncthreads();
    int e0 = bbase[k], e1 = bbase[k + 1];
    for (int e = e0 + t; e < e1; e += 256)
        atomicAdd(&cnt[part[e] >> 17], 1);
    __syncthreads();
    if (t == 0) {
        int run = 0;
        for (int i = 0; i < 256; ++i) { int c = cnt[i]; pos[i] = run; run += c; }
    }
    __syncthreads();
    int node = k * 256 + t;
    if (node < GNN_N) {
        rowptr[node] = e0 + pos[t];
        deg[node]    = cnt[t];
        dis[node]    = rsqrtf((float)cnt[t] + 1.0f);
    }
    __syncthreads();
    for (int e = e0 + t; e < e1; e += 256) {
        unsigned int p = part[e];
        int slot = e0 + atomicAdd(&pos[p >> 17], 1);
        csr[slot] = (int)(p & 0x1FFFF) << 7;   // byte offset into fp16 table
    }
}

// ---- tiled 64x64 matmul, fp16 output: Y[row] = fp16((X@W)[row]*dis[row]) ----
// TIN = float or __half; staging converts to f32 in LDS, inner loop unchanged.
template<typename TIN>
__global__ __launch_bounds__(256) void k_mm64h(const TIN* __restrict__ X,
                                               const float* __restrict__ W,
                                               const float* __restrict__ dis,
                                               __half* __restrict__ Y, int n) {
    __shared__ float  Xs[64][68];
    __shared__ float4 Wsh[64 * 16];
    int tid = threadIdx.x;
    int base = blockIdx.x * 64;
    for (int i = tid; i < 1024; i += 256)
        Wsh[i] = ((const float4*)W)[i];
    if constexpr (sizeof(TIN) == 4) {
#pragma unroll
        for (int i = 0; i < 4; ++i) {
            int g = i * 256 + tid;
            int r = g >> 4, c4 = g & 15;
            int row = base + r;
            float4 v = (row < n) ? ((const float4*)(X + (size_t)row * 64))[c4]
                                 : make_float4(0.f, 0.f, 0.f, 0.f);
            *(float4*)&Xs[r][c4 * 4] = v;
        }
    } else {
#pragma unroll
        for (int i = 0; i < 2; ++i) {       // 512 chunks of 8 halves
            int g = i * 256 + tid;
            int r = g >> 3, c8 = g & 7;
            int row = base + r;
            float f[8];
            if (row < n) {
                uint4 u = *(const uint4*)((const __half*)X + (size_t)row * 64 + c8 * 8);
                float2 t0 = __half22float2(*(__half2*)&u.x);
                float2 t1 = __half22float2(*(__half2*)&u.y);
                float2 t2 = __half22float2(*(__half2*)&u.z);
                float2 t3 = __half22float2(*(__half2*)&u.w);
                f[0] = t0.x; f[1] = t0.y; f[2] = t1.x; f[3] = t1.y;
                f[4] = t2.x; f[5] = t2.y; f[6] = t3.x; f[7] = t3.y;
            } else {
#pragma unroll
                for (int z = 0; z < 8; ++z) f[z] = 0.f;
            }
            *(float4*)&Xs[r][c8 * 8 + 0] = make_float4(f[0], f[1], f[2], f[3]);
            *(float4*)&Xs[r][c8 * 8 + 4] = make_float4(f[4], f[5], f[6], f[7]);
        }
    }
    __syncthreads();
    int tj = tid & 15;
    int ti = tid >> 4;
    float4 a0 = {0,0,0,0}, a1 = {0,0,0,0}, a2 = {0,0,0,0}, a3 = {0,0,0,0};
#pragma unroll 1
    for (int k4 = 0; k4 < 16; ++k4) {
        float4 x0 = *(const float4*)&Xs[ti * 4 + 0][k4 * 4];
        float4 x1 = *(const float4*)&Xs[ti * 4 + 1][k4 * 4];
        float4 x2 = *(const float4*)&Xs[ti * 4 + 2][k4 * 4];
        float4 x3 = *(const float4*)&Xs[ti * 4 + 3][k4 * 4];
        float4 w0 = Wsh[(k4 * 4 + 0) * 16 + tj];
        float4 w1 = Wsh[(k4 * 4 + 1) * 16 + tj];
        float4 w2 = Wsh[(k4 * 4 + 2) * 16 + tj];
        float4 w3 = Wsh[(k4 * 4 + 3) * 16 + tj];
#define FMA4(A, XV)                                                      \
        A.x += XV.x * w0.x + XV.y * w1.x + XV.z * w2.x + XV.w * w3.x;    \
        A.y += XV.x * w0.y + XV.y * w1.y + XV.z * w2.y + XV.w * w3.y;    \
        A.z += XV.x * w0.z + XV.y * w1.z + XV.z * w2.z + XV.w * w3.z;    \
        A.w += XV.x * w0.w + XV.y * w1.w + XV.z * w2.w + XV.w * w3.w;
        FMA4(a0, x0) FMA4(a1, x1) FMA4(a2, x2) FMA4(a3, x3)
#undef FMA4
    }
#pragma unroll
    for (int q = 0; q < 4; ++q) {
        int row = base + ti * 4 + q;
        if (row < n) {
            float d = dis[row];
            float4 a = (q == 0) ? a0 : (q == 1) ? a1 : (q == 2) ? a2 : a3;
            __half2 p0 = __floats2half2_rn(a.x * d, a.y * d);
            __half2 p1 = __floats2half2_rn(a.z * d, a.w * d);
            __half2* yp = (__half2*)(Y + (size_t)row * 64);
            yp[tj * 2 + 0] = p0;
            yp[tj * 2 + 1] = p1;
        }
    }
}

// ---- gather, group-per-node: wave = 8 nodes x 8 lanes; csr = byte offsets ----
#define ACC8(A, U) {                                                     \
    float2 f_;                                                           \
    f_ = __half22float2(*(__half2*)&U.x); A[0] += f_.x; A[1] += f_.y;    \
    f_ = __half22float2(*(__half2*)&U.y); A[2] += f_.x; A[3] += f_.y;    \
    f_ = __half22float2(*(__half2*)&U.z); A[4] += f_.x; A[5] += f_.y;    \
    f_ = __half22float2(*(__half2*)&U.w); A[6] += f_.x; A[7] += f_.y; }

// HEAD=false: writes fp16 row (pre-relu'd h1); HEAD=true: writes scalar f32.
template<bool HEAD>
__global__ __launch_bounds__(256) void k_gatherg(
        const __half* __restrict__ T, const int* __restrict__ csr,
        const int* __restrict__ rowptr, const int* __restrict__ deg,
        const float* __restrict__ dis, const float* __restrict__ bias,
        const float* __restrict__ Wp, const float* __restrict__ bp,
        void* __restrict__ outv, int n) {
    int tid = threadIdx.x;
    int q = tid & 7;                       // channel octet within group
    int node = blockIdx.x * 32 + (tid >> 3);
    if (node >= n) return;
    int base = rowptr[node];
    int cnt  = deg[node];
    float dd = dis[node];
    const char* Tq = (const char*)T + q * 16;   // + byte-offset per row
    float a0[8], a1[8];
#pragma unroll
    for (int i = 0; i < 8; ++i) { a0[i] = 0.f; a1[i] = 0.f; }
    int j = 0;
    for (; j + 4 <= cnt; j += 4) {          // 4 rows in flight per group
        int s0 = csr[base + j + 0];
        int s1 = csr[base + j + 1];
        int s2 = csr[base + j + 2];
        int s3 = csr[base + j + 3];
        uint4 u0 = *(const uint4*)(Tq + (size_t)(unsigned)s0);
        uint4 u1 = *(const uint4*)(Tq + (size_t)(unsigned)s1);
        uint4 u2 = *(const uint4*)(Tq + (size_t)(unsigned)s2);
        uint4 u3 = *(const uint4*)(Tq + (size_t)(unsigned)s3);
        ACC8(a0, u0)
        ACC8(a1, u1)
        ACC8(a0, u2)
        ACC8(a1, u3)
    }
    if (j + 2 <= cnt) {
        int s0 = csr[base + j + 0];
        int s1 = csr[base + j + 1];
        uint4 u0 = *(const uint4*)(Tq + (size_t)(unsigned)s0);
        uint4 u1 = *(const uint4*)(Tq + (size_t)(unsigned)s1);
        ACC8(a0, u0)
        ACC8(a1, u1)
        j += 2;
    }
    if (j < cnt) {
        int s = csr[base + j];
        uint4 u = *(const uint4*)(Tq + (size_t)(unsigned)s);
        ACC8(a0, u)
    }
    uint4 us = *(const uint4*)(Tq + (size_t)node * 128);   // self row
    ACC8(a1, us)
    float4 bb0 = ((const float4*)bias)[q * 2 + 0];
    float4 bb1 = ((const float4*)bias)[q * 2 + 1];
    float r[8];
    r[0] = fmaxf(dd * (a0[0] + a1[0]) + bb0.x, 0.f);
    r[1] = fmaxf(dd * (a0[1] + a1[1]) + bb0.y, 0.f);
    r[2] = fmaxf(dd * (a0[2] + a1[2]) + bb0.z, 0.f);
    r[3] = fmaxf(dd * (a0[3] + a1[3]) + bb0.w, 0.f);
    r[4] = fmaxf(dd * (a0[4] + a1[4]) + bb1.x, 0.f);
    r[5] = fmaxf(dd * (a0[5] + a1[5]) + bb1.y, 0.f);
    r[6] = fmaxf(dd * (a0[6] + a1[6]) + bb1.z, 0.f);
    r[7] = fmaxf(dd * (a0[7] + a1[7]) + bb1.w, 0.f);
    if constexpr (HEAD) {
        float4 w0 = ((const float4*)Wp)[q * 2 + 0];
        float4 w1 = ((const float4*)Wp)[q * 2 + 1];
        float s = r[0] * w0.x + r[1] * w0.y + r[2] * w0.z + r[3] * w0.w
                + r[4] * w1.x + r[5] * w1.y + r[6] * w1.z + r[7] * w1.w;
#pragma unroll
        for (int m = 1; m <= 4; m <<= 1) s += __shfl_xor(s, m);
        if (q == 0) ((float*)outv)[node] = s + bp[0];
    } else {
        __half* op = (__half*)outv + (size_t)node * 64 + q * 8;
        __half2 h0 = __floats2half2_rn(r[0], r[1]);
        __half2 h1 = __floats2half2_rn(r[2], r[3]);
        __half2 h2 = __floats2half2_rn(r[4], r[5]);
        __half2 h3 = __floats2half2_rn(r[6], r[7]);
        uint4 u;
        *(__half2*)&u.x = h0; *(__half2*)&u.y = h1;
        *(__half2*)&u.z = h2; *(__half2*)&u.w = h3;
        *(uint4*)op = u;
    }
}

extern "C" void kernel_launch(void* const* d_in, const int* in_sizes, int n_in,
                              void* d_out, int out_size, void* d_ws, size_t ws_size,
                              hipStream_t stream) {
    const float* x  = (const float*)d_in[0];
    const int*   ei = (const int*)d_in[1];
    const float* W1 = (const float*)d_in[2];
    const float* b1 = (const float*)d_in[3];
    const float* W2 = (const float*)d_in[4];
    const float* b2 = (const float*)d_in[5];
    const float* Wp = (const float*)d_in[6];
    const float* bp = (const float*)d_in[7];
    float* out = (float*)d_out;

    const int N = GNN_N, E = GNN_E;
    const int* srcv = ei;
    const int* dstv = ei + E;

    // workspace layout (bytes):
    //   hist @ 0           : NBLK*NBUCK ints
    //   bbase @ 400,896    : 392 ints
    //   rowptr @ 402,944   : N ints
    //   deg @ 802,944      : N ints
    //   dis/tot @ 1,202,944: N floats (tot aliases dis; dis written by bsort)
    //   csr @ 1,603,584    : E ints (6.4 MB, BYTE offsets)
    //   TA  @ 8,003,584    : N*64 fp16 (12.8 MB)
    //   h1h @ 20,803,584   : N*64 fp16 (12.8 MB)
    //   TB  @ 33,603,584   : N*64 fp16 (12.8 MB)
    //   part @ 46,403,584  : E u32 (6.4 MB)   [total 52.8 MB]
    char* ws = (char*)d_ws;
    int*    hist   = (int*)(ws + 0);
    int*    bbase  = (int*)(ws + 400896);
    int*    rowptr = (int*)(ws + 402944);
    int*    deg    = (int*)(ws + 802944);
    float*  dis    = (float*)(ws + 1202944);
    int*    tot    = (int*)(ws + 1202944);
    int*    csr    = (int*)(ws + 1603584);
    __half* TA     = (__half*)(ws + 8003584);
    __half* h1h    = (__half*)(ws + 20803584);
    __half* TB     = (__half*)(ws + 33603584);
    unsigned int* part = (unsigned int*)(ws + 46403584);

    // CSR build
    k_hist <<<NBLK, 256, 0, stream>>>(dstv, hist);
    k_cscan<<<(NBUCK + SCTILE - 1) / SCTILE, 256, 0, stream>>>(hist, tot);
    k_btot <<<1, 512, 0, stream>>>(tot, bbase);
    k_part <<<NBLK, 256, 0, stream>>>(srcv, dstv, hist, bbase, part);
    k_bsort<<<NBUCK, 256, 0, stream>>>(part, bbase, csr, rowptr, deg, dis);

    // layer 1: TA = fp16((x@W1)*dis) ; h1h = fp16(relu(gather))
    k_mm64h<float><<<(N + 63) / 64, 256, 0, stream>>>(x, W1, dis, TA, N);
    k_gatherg<false><<<(N + 31) / 32, 256, 0, stream>>>(TA, csr, rowptr, deg, dis,
                                                        b1, nullptr, nullptr, h1h, N);
    // layer 2 + head: TB = fp16((h1h@W2)*dis) ; out = head(relu(gather))
    k_mm64h<__half><<<(N + 63) / 64, 256, 0, stream>>>(h1h, W2, dis, TB, N);
    k_gatherg<true><<<(N + 31) / 32, 256, 0, stream>>>(TB, csr, rowptr, deg, dis,
                                                       b2, Wp, bp, out, N);
}

// Round 11
// 147.699 us; speedup vs baseline: 2.0359x; 1.0341x over previous
//
#include <hip/hip_runtime.h>
#include <hip/hip_fp16.h>

// BusStopGNN round 11: CSR-build vectorization + tail-free padded gather.
//  - k_hist/k_part: int4 edge sweeps (NBLK=250, EPB=6400 %4==0).
//  - k_bsort: bucket staged in LDS once (no second global read); emits
//    4-PADDED per-node runs (dummy slots -> zero row at table index N).
//  - k_gatherg: aligned int4 csr loads, 8 rows in flight, zero tail code.
// fp16 tables & h1, group-per-node gather, rolled-k mm64h unchanged.

#define GNN_N 100000
#define GNN_E 1600000
#define NBUCK 391       // ceil(N/256), bucket = dst >> 8
#define NBLK  250
#define EPB   6400      // E / NBLK, divisible by 4
#define SCTILE 16
#define STAGE_CAP 4864  // bucket mean 4092, sigma 64 -> overflow ~never
#define DUMMY_OFF (GNN_N * 128)   // byte offset of zero row in fp16 tables

// ---- Pass 1: per-block LDS histogram (int4 sweep) + zero-row init ----
__global__ __launch_bounds__(256) void k_hist(const int* __restrict__ dst,
                                              int* __restrict__ hist,
                                              __half* __restrict__ TA,
                                              __half* __restrict__ TB) {
    __shared__ int h[NBUCK];
    for (int i = threadIdx.x; i < NBUCK; i += 256) h[i] = 0;
    if (blockIdx.x == 0 && threadIdx.x < 16) {     // zero row N of both tables
        uint4 z = {0, 0, 0, 0};
        int t = threadIdx.x;
        __half* base = (t < 8) ? TA : TB;
        *(uint4*)((char*)base + DUMMY_OFF + (t & 7) * 16) = z;
    }
    __syncthreads();
    int b = blockIdx.x;
    int e0 = b * EPB, e1 = min(e0 + EPB, GNN_E);
    for (int e = e0 + threadIdx.x * 4; e < e1; e += 1024) {
        int4 d = *(const int4*)(dst + e);
        atomicAdd(&h[d.x >> 8], 1);
        atomicAdd(&h[d.y >> 8], 1);
        atomicAdd(&h[d.z >> 8], 1);
        atomicAdd(&h[d.w >> 8], 1);
    }
    __syncthreads();
    for (int i = threadIdx.x; i < NBUCK; i += 256)
        hist[b * NBUCK + i] = h[i];
}

// ---- Pass 2a: tiled column scan (rows 0..NBLK-1) ----
__global__ __launch_bounds__(256) void k_cscan(int* __restrict__ hist,
                                               int* __restrict__ tot) {
    __shared__ int tile[256][SCTILE + 1];
    int k0 = blockIdx.x * SCTILE;
    int b = threadIdx.x;
#pragma unroll
    for (int i = 0; i < SCTILE; ++i) {
        int k = k0 + i;
        tile[b][i] = (k < NBUCK && b < NBLK) ? hist[b * NBUCK + k] : 0;
    }
    __syncthreads();
    int lane = b & 63, w = b >> 6;
    int cSub = lane >> 4;
    int l16 = lane & 15;
    int col = w * 4 + cSub;
    int run = 0;
    for (int chunk = 0; chunk < 16; ++chunk) {
        int idx = chunk * 16 + l16;
        int v = tile[idx][col];
        int s = v;
#pragma unroll
        for (int o = 1; o < 16; o <<= 1) {
            int t = __shfl_up(s, o);
            if (l16 >= o) s += t;
        }
        tile[idx][col] = s - v + run;
        run += __shfl(s, lane | 15);
    }
    if (l16 == 0 && k0 + col < NBUCK) tot[k0 + col] = run;
    __syncthreads();
#pragma unroll
    for (int i = 0; i < SCTILE; ++i) {
        int k = k0 + i;
        if (k < NBUCK && b < NBLK) hist[b * NBUCK + k] = tile[b][i];
    }
}

// ---- Pass 2b: scan bucket totals -> bbase (real) + cbase (padded csr) ----
__global__ __launch_bounds__(512) void k_btot(const int* __restrict__ tot,
                                              int* __restrict__ bbase,
                                              int* __restrict__ cbase) {
    __shared__ int s[NBUCK];
    int t = threadIdx.x;
    if (t < NBUCK) s[t] = tot[t];
    __syncthreads();
    if (t == 0) {
        int run = 0;
        for (int i = 0; i < NBUCK; ++i) { int v = s[i]; s[i] = run; run += v; }
    }
    __syncthreads();
    if (t < NBUCK) {
        bbase[t] = s[t];
        cbase[t] = (s[t] & ~3) + t * 772;   // 4-aligned, capacity real+769 >= padded
    }
    if (t == 0) bbase[NBUCK] = GNN_E;
}

// ---- Pass 3: partition edges (int4 sweep); pack (dst&255)<<17 | src ----
__global__ __launch_bounds__(256) void k_part(const int* __restrict__ src,
                                              const int* __restrict__ dst,
                                              const int* __restrict__ hist,
                                              const int* __restrict__ bbase,
                                              unsigned int* __restrict__ part) {
    __shared__ int off[NBUCK];
    int b = blockIdx.x;
    for (int i = threadIdx.x; i < NBUCK; i += 256)
        off[i] = bbase[i] + hist[b * NBUCK + i];
    __syncthreads();
    int e0 = b * EPB, e1 = min(e0 + EPB, GNN_E);
    for (int e = e0 + threadIdx.x * 4; e < e1; e += 1024) {
        int4 d = *(const int4*)(dst + e);
        int4 s = *(const int4*)(src + e);
        int sl0 = atomicAdd(&off[d.x >> 8], 1);
        part[sl0] = ((unsigned int)(d.x & 255) << 17) | (unsigned int)s.x;
        int sl1 = atomicAdd(&off[d.y >> 8], 1);
        part[sl1] = ((unsigned int)(d.y & 255) << 17) | (unsigned int)s.y;
        int sl2 = atomicAdd(&off[d.z >> 8], 1);
        part[sl2] = ((unsigned int)(d.z & 255) << 17) | (unsigned int)s.z;
        int sl3 = atomicAdd(&off[d.w >> 8], 1);
        part[sl3] = ((unsigned int)(d.w & 255) << 17) | (unsigned int)s.w;
    }
}

// ---- Pass 4: per-bucket sort, LDS-staged single read, 4-padded runs ----
__global__ __launch_bounds__(256) void k_bsort(const unsigned int* __restrict__ part,
                                               const int* __restrict__ bbase,
                                               const int* __restrict__ cbase,
                                               int* __restrict__ csr,
                                               int* __restrict__ rowptr,
                                               int* __restrict__ deg,
                                               float* __restrict__ dis) {
    __shared__ int cnt[256];
    __shared__ int pstart[256];
    __shared__ int bump[256];
    __shared__ unsigned int stage[STAGE_CAP];
    int k = blockIdx.x;
    int t = threadIdx.x;
    cnt[t] = 0;
    __syncthreads();
    int e0 = bbase[k], e1 = bbase[k + 1];
    int m = e1 - e0;
    bool fits = (m <= STAGE_CAP);
    for (int i = t; i < m; i += 256) {
        unsigned int p = part[e0 + i];
        if (fits) stage[i] = p;
        atomicAdd(&cnt[p >> 17], 1);
    }
    __syncthreads();
    if (t == 0) {
        int run = 0;
        for (int i = 0; i < 256; ++i) {
            pstart[i] = run;
            run += (cnt[i] + 3) & ~3;     // padded run
        }
    }
    __syncthreads();
    int cb = cbase[k];
    int node = k * 256 + t;
    if (node < GNN_N) {
        int c = cnt[t];
        rowptr[node] = cb + pstart[t];
        deg[node]    = (c + 3) & ~3;      // padded count (gather)
        dis[node]    = rsqrtf((float)c + 1.0f);   // true degree (norm)
    }
    bump[t] = pstart[t];
    __syncthreads();
    for (int i = t; i < m; i += 256) {
        unsigned int p = fits ? stage[i] : part[e0 + i];
        int slot = atomicAdd(&bump[p >> 17], 1);
        csr[cb + slot] = (int)(p & 0x1FFFF) << 7;   // byte offset
    }
    __syncthreads();
    if (node < GNN_N) {
        int c = cnt[t], pc = (c + 3) & ~3;
        for (int i = c; i < pc; ++i)
            csr[cb + pstart[t] + i] = DUMMY_OFF;    // zero row
    }
}

// ---- tiled 64x64 matmul, fp16 output: Y[row] = fp16((X@W)[row]*dis[row]) ----
template<typename TIN>
__global__ __launch_bounds__(256) void k_mm64h(const TIN* __restrict__ X,
                                               const float* __restrict__ W,
                                               const float* __restrict__ dis,
                                               __half* __restrict__ Y, int n) {
    __shared__ float  Xs[64][68];
    __shared__ float4 Wsh[64 * 16];
    int tid = threadIdx.x;
    int base = blockIdx.x * 64;
    for (int i = tid; i < 1024; i += 256)
        Wsh[i] = ((const float4*)W)[i];
    if constexpr (sizeof(TIN) == 4) {
#pragma unroll
        for (int i = 0; i < 4; ++i) {
            int g = i * 256 + tid;
            int r = g >> 4, c4 = g & 15;
            int row = base + r;
            float4 v = (row < n) ? ((const float4*)(X + (size_t)row * 64))[c4]
                                 : make_float4(0.f, 0.f, 0.f, 0.f);
            *(float4*)&Xs[r][c4 * 4] = v;
        }
    } else {
#pragma unroll
        for (int i = 0; i < 2; ++i) {
            int g = i * 256 + tid;
            int r = g >> 3, c8 = g & 7;
            int row = base + r;
            float f[8];
            if (row < n) {
                uint4 u = *(const uint4*)((const __half*)X + (size_t)row * 64 + c8 * 8);
                float2 t0 = __half22float2(*(__half2*)&u.x);
                float2 t1 = __half22float2(*(__half2*)&u.y);
                float2 t2 = __half22float2(*(__half2*)&u.z);
                float2 t3 = __half22float2(*(__half2*)&u.w);
                f[0] = t0.x; f[1] = t0.y; f[2] = t1.x; f[3] = t1.y;
                f[4] = t2.x; f[5] = t2.y; f[6] = t3.x; f[7] = t3.y;
            } else {
#pragma unroll
                for (int z = 0; z < 8; ++z) f[z] = 0.f;
            }
            *(float4*)&Xs[r][c8 * 8 + 0] = make_float4(f[0], f[1], f[2], f[3]);
            *(float4*)&Xs[r][c8 * 8 + 4] = make_float4(f[4], f[5], f[6], f[7]);
        }
    }
    __syncthreads();
    int tj = tid & 15;
    int ti = tid >> 4;
    float4 a0 = {0,0,0,0}, a1 = {0,0,0,0}, a2 = {0,0,0,0}, a3 = {0,0,0,0};
#pragma unroll 1
    for (int k4 = 0; k4 < 16; ++k4) {
        float4 x0 = *(const float4*)&Xs[ti * 4 + 0][k4 * 4];
        float4 x1 = *(const float4*)&Xs[ti * 4 + 1][k4 * 4];
        float4 x2 = *(const float4*)&Xs[ti * 4 + 2][k4 * 4];
        float4 x3 = *(const float4*)&Xs[ti * 4 + 3][k4 * 4];
        float4 w0 = Wsh[(k4 * 4 + 0) * 16 + tj];
        float4 w1 = Wsh[(k4 * 4 + 1) * 16 + tj];
        float4 w2 = Wsh[(k4 * 4 + 2) * 16 + tj];
        float4 w3 = Wsh[(k4 * 4 + 3) * 16 + tj];
#define FMA4(A, XV)                                                      \
        A.x += XV.x * w0.x + XV.y * w1.x + XV.z * w2.x + XV.w * w3.x;    \
        A.y += XV.x * w0.y + XV.y * w1.y + XV.z * w2.y + XV.w * w3.y;    \
        A.z += XV.x * w0.z + XV.y * w1.z + XV.z * w2.z + XV.w * w3.z;    \
        A.w += XV.x * w0.w + XV.y * w1.w + XV.z * w2.w + XV.w * w3.w;
        FMA4(a0, x0) FMA4(a1, x1) FMA4(a2, x2) FMA4(a3, x3)
#undef FMA4
    }
#pragma unroll
    for (int q = 0; q < 4; ++q) {
        int row = base + ti * 4 + q;
        if (row < n) {
            float d = dis[row];
            float4 a = (q == 0) ? a0 : (q == 1) ? a1 : (q == 2) ? a2 : a3;
            __half2 p0 = __floats2half2_rn(a.x * d, a.y * d);
            __half2 p1 = __floats2half2_rn(a.z * d, a.w * d);
            __half2* yp = (__half2*)(Y + (size_t)row * 64);
            yp[tj * 2 + 0] = p0;
            yp[tj * 2 + 1] = p1;
        }
    }
}

// ---- gather, group-per-node; padded runs -> int4 csr loads, no tails ----
#define ACC8(A, U) {                                                     \
    float2 f_;                                                           \
    f_ = __half22float2(*(__half2*)&U.x); A[0] += f_.x; A[1] += f_.y;    \
    f_ = __half22float2(*(__half2*)&U.y); A[2] += f_.x; A[3] += f_.y;    \
    f_ = __half22float2(*(__half2*)&U.z); A[4] += f_.x; A[5] += f_.y;    \
    f_ = __half22float2(*(__half2*)&U.w); A[6] += f_.x; A[7] += f_.y; }

template<bool HEAD>
__global__ __launch_bounds__(256) void k_gatherg(
        const __half* __restrict__ T, const int* __restrict__ csr,
        const int* __restrict__ rowptr, const int* __restrict__ deg,
        const float* __restrict__ dis, const float* __restrict__ bias,
        const float* __restrict__ Wp, const float* __restrict__ bp,
        void* __restrict__ outv, int n) {
    int tid = threadIdx.x;
    int q = tid & 7;                       // channel octet within group
    int node = blockIdx.x * 32 + (tid >> 3);
    if (node >= n) return;
    int base = rowptr[node];               // 4-aligned
    int cnt  = deg[node];                  // multiple of 4
    float dd = dis[node];
    const char* Tq = (const char*)T + q * 16;
    float a0[8], a1[8];
#pragma unroll
    for (int i = 0; i < 8; ++i) { a0[i] = 0.f; a1[i] = 0.f; }
    int j = 0;
    for (; j + 8 <= cnt; j += 8) {          // 8 rows in flight per group
        int4 c0 = *(const int4*)(csr + base + j);
        int4 c1 = *(const int4*)(csr + base + j + 4);
        uint4 u0 = *(const uint4*)(Tq + (size_t)(unsigned)c0.x);
        uint4 u1 = *(const uint4*)(Tq + (size_t)(unsigned)c0.y);
        uint4 u2 = *(const uint4*)(Tq + (size_t)(unsigned)c0.z);
        uint4 u3 = *(const uint4*)(Tq + (size_t)(unsigned)c0.w);
        uint4 u4 = *(const uint4*)(Tq + (size_t)(unsigned)c1.x);
        uint4 u5 = *(const uint4*)(Tq + (size_t)(unsigned)c1.y);
        uint4 u6 = *(const uint4*)(Tq + (size_t)(unsigned)c1.z);
        uint4 u7 = *(const uint4*)(Tq + (size_t)(unsigned)c1.w);
        ACC8(a0, u0) ACC8(a1, u1) ACC8(a0, u2) ACC8(a1, u3)
        ACC8(a0, u4) ACC8(a1, u5) ACC8(a0, u6) ACC8(a1, u7)
    }
    if (j < cnt) {                          // exactly 4 remain
        int4 c0 = *(const int4*)(csr + base + j);
        uint4 u0 = *(const uint4*)(Tq + (size_t)(unsigned)c0.x);
        uint4 u1 = *(const uint4*)(Tq + (size_t)(unsigned)c0.y);
        uint4 u2 = *(const uint4*)(Tq + (size_t)(unsigned)c0.z);
        uint4 u3 = *(const uint4*)(Tq + (size_t)(unsigned)c0.w);
        ACC8(a0, u0) ACC8(a1, u1) ACC8(a0, u2) ACC8(a1, u3)
    }
    uint4 us = *(const uint4*)(Tq + (size_t)node * 128);   // self row
    ACC8(a1, us)
    float4 bb0 = ((const float4*)bias)[q * 2 + 0];
    float4 bb1 = ((const float4*)bias)[q * 2 + 1];
    float r[8];
    r[0] = fmaxf(dd * (a0[0] + a1[0]) + bb0.x, 0.f);
    r[1] = fmaxf(dd * (a0[1] + a1[1]) + bb0.y, 0.f);
    r[2] = fmaxf(dd * (a0[2] + a1[2]) + bb0.z, 0.f);
    r[3] = fmaxf(dd * (a0[3] + a1[3]) + bb0.w, 0.f);
    r[4] = fmaxf(dd * (a0[4] + a1[4]) + bb1.x, 0.f);
    r[5] = fmaxf(dd * (a0[5] + a1[5]) + bb1.y, 0.f);
    r[6] = fmaxf(dd * (a0[6] + a1[6]) + bb1.z, 0.f);
    r[7] = fmaxf(dd * (a0[7] + a1[7]) + bb1.w, 0.f);
    if constexpr (HEAD) {
        float4 w0 = ((const float4*)Wp)[q * 2 + 0];
        float4 w1 = ((const float4*)Wp)[q * 2 + 1];
        float s = r[0] * w0.x + r[1] * w0.y + r[2] * w0.z + r[3] * w0.w
                + r[4] * w1.x + r[5] * w1.y + r[6] * w1.z + r[7] * w1.w;
#pragma unroll
        for (int m = 1; m <= 4; m <<= 1) s += __shfl_xor(s, m);
        if (q == 0) ((float*)outv)[node] = s + bp[0];
    } else {
        __half* op = (__half*)outv + (size_t)node * 64 + q * 8;
        __half2 h0 = __floats2half2_rn(r[0], r[1]);
        __half2 h1 = __floats2half2_rn(r[2], r[3]);
        __half2 h2 = __floats2half2_rn(r[4], r[5]);
        __half2 h3 = __floats2half2_rn(r[6], r[7]);
        uint4 u;
        *(__half2*)&u.x = h0; *(__half2*)&u.y = h1;
        *(__half2*)&u.z = h2; *(__half2*)&u.w = h3;
        *(uint4*)op = u;
    }
}

extern "C" void kernel_launch(void* const* d_in, const int* in_sizes, int n_in,
                              void* d_out, int out_size, void* d_ws, size_t ws_size,
                              hipStream_t stream) {
    const float* x  = (const float*)d_in[0];
    const int*   ei = (const int*)d_in[1];
    const float* W1 = (const float*)d_in[2];
    const float* b1 = (const float*)d_in[3];
    const float* W2 = (const float*)d_in[4];
    const float* b2 = (const float*)d_in[5];
    const float* Wp = (const float*)d_in[6];
    const float* bp = (const float*)d_in[7];
    float* out = (float*)d_out;

    const int N = GNN_N, E = GNN_E;
    const int* srcv = ei;
    const int* dstv = ei + E;

    // workspace layout (bytes):
    //   hist   @ 0         : NBLK*NBUCK ints (391,000)
    //   bbase  @ 392,000   : 392 ints
    //   cbase  @ 393,600   : 392 ints
    //   rowptr @ 395,264   : N ints
    //   deg    @ 795,264   : N ints
    //   dis/tot@ 1,195,264 : N floats (tot aliases dis; dis written by bsort)
    //   csr    @ 1,595,392 : ~1.91M ints padded (7.61 MB)
    //   TA     @ 9,600,000 : (N+1)*64 fp16 (12.8 MB + zero row)
    //   h1h    @ 22,400,256: N*64 fp16
    //   TB     @ 35,200,384: (N+1)*64 fp16
    //   part   @ 48,000,512: E u32 (6.4 MB)  [total ~54.4 MB]
    char* ws = (char*)d_ws;
    int*    hist   = (int*)(ws + 0);
    int*    bbase  = (int*)(ws + 392000);
    int*    cbase  = (int*)(ws + 393600);
    int*    rowptr = (int*)(ws + 395264);
    int*    deg    = (int*)(ws + 795264);
    float*  dis    = (float*)(ws + 1195264);
    int*    tot    = (int*)(ws + 1195264);
    int*    csr    = (int*)(ws + 1595392);
    __half* TA     = (__half*)(ws + 9600000);
    __half* h1h    = (__half*)(ws + 22400256);
    __half* TB     = (__half*)(ws + 35200384);
    unsigned int* part = (unsigned int*)(ws + 48000512);

    // CSR build
    k_hist <<<NBLK, 256, 0, stream>>>(dstv, hist, TA, TB);
    k_cscan<<<(NBUCK + SCTILE - 1) / SCTILE, 256, 0, stream>>>(hist, tot);
    k_btot <<<1, 512, 0, stream>>>(tot, bbase, cbase);
    k_part <<<NBLK, 256, 0, stream>>>(srcv, dstv, hist, bbase, part);
    k_bsort<<<NBUCK, 256, 0, stream>>>(part, bbase, cbase, csr, rowptr, deg, dis);

    // layer 1: TA = fp16((x@W1)*dis) ; h1h = fp16(relu(gather))
    k_mm64h<float><<<(N + 63) / 64, 256, 0, stream>>>(x, W1, dis, TA, N);
    k_gatherg<false><<<(N + 31) / 32, 256, 0, stream>>>(TA, csr, rowptr, deg, dis,
                                                        b1, nullptr, nullptr, h1h, N);
    // layer 2 + head: TB = fp16((h1h@W2)*dis) ; out = head(relu(gather))
    k_mm64h<__half><<<(N + 63) / 64, 256, 0, stream>>>(h1h, W2, dis, TB, N);
    k_gatherg<true><<<(N + 31) / 32, 256, 0, stream>>>(TB, csr, rowptr, deg, dis,
                                                       b2, Wp, bp, out, N);
}

// Round 12
// 132.039 us; speedup vs baseline: 2.2774x; 1.1186x over previous
//
#include <hip/hip_runtime.h>
#include <hip/hip_fp16.h>

// BusStopGNN round 12:
//  - matmuls -> MFMA (mfma_f32_16x16x32_f16): X,W^T staged fp16 in LDS,
//    4 waves x 16-row bands, f32 accum, dis epilogue, LDS-bounce store.
//  - hist at 500 blocks (2/CU); cscan 2-pass over 500 rows; part stays at
//    250 blocks (line-exclusive writes) reading hist row 2b.
//  - btot/bsort scans parallelized (Hillis-Steele / wave shfl).
// Group-per-node padded gather and fp16 tables unchanged from round 11.

#define GNN_N 100000
#define GNN_E 1600000
#define NBUCK 391       // ceil(N/256), bucket = dst >> 8
#define HBLK  500       // hist blocks
#define EPBH  3200      // E / HBLK, %4 == 0
#define NBLK  250       // part blocks
#define EPB   6400      // E / NBLK, %4 == 0
#define SCTILE 16
#define STAGE_CAP 4864
#define DUMMY_OFF (GNN_N * 128)   // byte offset of zero row in fp16 tables

typedef _Float16 half8 __attribute__((ext_vector_type(8)));
typedef float f32x4 __attribute__((ext_vector_type(4)));

// ---- Pass 1: per-block LDS histogram (int4 sweep) + zero-row init ----
__global__ __launch_bounds__(256) void k_hist(const int* __restrict__ dst,
                                              int* __restrict__ hist,
                                              __half* __restrict__ TA,
                                              __half* __restrict__ TB) {
    __shared__ int h[NBUCK];
    for (int i = threadIdx.x; i < NBUCK; i += 256) h[i] = 0;
    if (blockIdx.x == 0 && threadIdx.x < 16) {     // zero row N of both tables
        uint4 z = {0, 0, 0, 0};
        int t = threadIdx.x;
        __half* base = (t < 8) ? TA : TB;
        *(uint4*)((char*)base + DUMMY_OFF + (t & 7) * 16) = z;
    }
    __syncthreads();
    int b = blockIdx.x;
    int e0 = b * EPBH, e1 = min(e0 + EPBH, GNN_E);
    for (int e = e0 + threadIdx.x * 4; e < e1; e += 1024) {
        int4 d = *(const int4*)(dst + e);
        atomicAdd(&h[d.x >> 8], 1);
        atomicAdd(&h[d.y >> 8], 1);
        atomicAdd(&h[d.z >> 8], 1);
        atomicAdd(&h[d.w >> 8], 1);
    }
    __syncthreads();
    for (int i = threadIdx.x; i < NBUCK; i += 256)
        hist[b * NBUCK + i] = h[i];
}

// ---- Pass 2a: tiled column scan over HBLK rows (2 passes of 256) ----
__global__ __launch_bounds__(256) void k_cscan(int* __restrict__ hist,
                                               int* __restrict__ tot) {
    __shared__ int tile[256][SCTILE + 1];
    int k0 = blockIdx.x * SCTILE;
    int b = threadIdx.x;
    int lane = b & 63, w = b >> 6;
    int cSub = lane >> 4;
    int l16 = lane & 15;
    int col = w * 4 + cSub;
    int run = 0;
    for (int pass = 0; pass < 2; ++pass) {
        int r = pass * 256 + b;
#pragma unroll
        for (int i = 0; i < SCTILE; ++i) {
            int k = k0 + i;
            tile[b][i] = (k < NBUCK && r < HBLK) ? hist[r * NBUCK + k] : 0;
        }
        __syncthreads();
        for (int chunk = 0; chunk < 16; ++chunk) {
            int idx = chunk * 16 + l16;
            int v = tile[idx][col];
            int s = v;
#pragma unroll
            for (int o = 1; o < 16; o <<= 1) {
                int t = __shfl_up(s, o);
                if (l16 >= o) s += t;
            }
            tile[idx][col] = s - v + run;
            run += __shfl(s, lane | 15);
        }
        __syncthreads();
#pragma unroll
        for (int i = 0; i < SCTILE; ++i) {
            int k = k0 + i;
            if (k < NBUCK && r < HBLK) hist[r * NBUCK + k] = tile[b][i];
        }
        __syncthreads();
    }
    if (l16 == 0 && k0 + col < NBUCK) tot[k0 + col] = run;
}

// ---- Pass 2b: parallel scan of bucket totals -> bbase, cbase ----
__global__ __launch_bounds__(512) void k_btot(const int* __restrict__ tot,
                                              int* __restrict__ bbase,
                                              int* __restrict__ cbase) {
    __shared__ int s[512];
    int t = threadIdx.x;
    int own = (t < NBUCK) ? tot[t] : 0;
    s[t] = own;
    __syncthreads();
    for (int off = 1; off < 512; off <<= 1) {      // Hillis-Steele inclusive
        int v = (t >= off) ? s[t - off] : 0;
        __syncthreads();
        s[t] += v;
        __syncthreads();
    }
    if (t < NBUCK) {
        int ex = s[t] - own;                       // exclusive prefix
        bbase[t] = ex;
        cbase[t] = (ex & ~3) + t * 772;            // 4-aligned padded base
    }
    if (t == 0) bbase[NBUCK] = GNN_E;
}

// ---- Pass 3: partition edges (int4); pack (dst&255)<<17 | src ----
__global__ __launch_bounds__(256) void k_part(const int* __restrict__ src,
                                              const int* __restrict__ dst,
                                              const int* __restrict__ hist,
                                              const int* __restrict__ bbase,
                                              unsigned int* __restrict__ part) {
    __shared__ int off[NBUCK];
    int b = blockIdx.x;
    for (int i = threadIdx.x; i < NBUCK; i += 256)
        off[i] = bbase[i] + hist[(2 * b) * NBUCK + i];   // prefix at hist row 2b
    __syncthreads();
    int e0 = b * EPB, e1 = min(e0 + EPB, GNN_E);
    for (int e = e0 + threadIdx.x * 4; e < e1; e += 1024) {
        int4 d = *(const int4*)(dst + e);
        int4 s = *(const int4*)(src + e);
        int sl0 = atomicAdd(&off[d.x >> 8], 1);
        part[sl0] = ((unsigned int)(d.x & 255) << 17) | (unsigned int)s.x;
        int sl1 = atomicAdd(&off[d.y >> 8], 1);
        part[sl1] = ((unsigned int)(d.y & 255) << 17) | (unsigned int)s.y;
        int sl2 = atomicAdd(&off[d.z >> 8], 1);
        part[sl2] = ((unsigned int)(d.z & 255) << 17) | (unsigned int)s.z;
        int sl3 = atomicAdd(&off[d.w >> 8], 1);
        part[sl3] = ((unsigned int)(d.w & 255) << 17) | (unsigned int)s.w;
    }
}

// ---- Pass 4: per-bucket sort, LDS-staged, 4-padded runs, parallel scan ----
__global__ __launch_bounds__(256) void k_bsort(const unsigned int* __restrict__ part,
                                               const int* __restrict__ bbase,
                                               const int* __restrict__ cbase,
                                               int* __restrict__ csr,
                                               int* __restrict__ rowptr,
                                               int* __restrict__ deg,
                                               float* __restrict__ dis) {
    __shared__ int cnt[256];
    __shared__ int pstart[256];
    __shared__ int bump[256];
    __shared__ int wtot[4];
    __shared__ unsigned int stage[STAGE_CAP];
    int k = blockIdx.x;
    int t = threadIdx.x;
    cnt[t] = 0;
    __syncthreads();
    int e0 = bbase[k], e1 = bbase[k + 1];
    int m = e1 - e0;
    bool fits = (m <= STAGE_CAP);
    for (int i = t; i < m; i += 256) {
        unsigned int p = part[e0 + i];
        if (fits) stage[i] = p;
        atomicAdd(&cnt[p >> 17], 1);
    }
    __syncthreads();
    // wave-parallel exclusive scan of padded counts
    int c = cnt[t];
    int padded = (c + 3) & ~3;
    int v = padded;
#pragma unroll
    for (int o = 1; o < 64; o <<= 1) {
        int u = __shfl_up(v, o);
        if ((t & 63) >= o) v += u;
    }
    if ((t & 63) == 63) wtot[t >> 6] = v;
    __syncthreads();
    int wb = 0;
#pragma unroll
    for (int j = 0; j < 4; ++j)
        if (j < (t >> 6)) wb += wtot[j];
    pstart[t] = wb + v - padded;
    bump[t] = pstart[t];
    __syncthreads();
    int cb = cbase[k];
    int node = k * 256 + t;
    if (node < GNN_N) {
        rowptr[node] = cb + pstart[t];
        deg[node]    = padded;                    // padded count (gather)
        dis[node]    = rsqrtf((float)c + 1.0f);   // true degree (norm)
    }
    for (int i = t; i < m; i += 256) {
        unsigned int p = fits ? stage[i] : part[e0 + i];
        int slot = atomicAdd(&bump[p >> 17], 1);
        csr[cb + slot] = (int)(p & 0x1FFFF) << 7; // byte offset
    }
    __syncthreads();
    if (node < GNN_N) {
        for (int i = c; i < padded; ++i)
            csr[cb + pstart[t] + i] = DUMMY_OFF;  // zero row
    }
}

// ---- MFMA 64x64 matmul, fp16 out: Y[row] = fp16((X@W)[row]*dis[row]) ----
// 4 waves; wave w computes rows w*16..w*16+15 via mfma_f32_16x16x32_f16:
// 4 col-tiles x 2 k-halves. X, W^T staged fp16 in LDS; D bounced via LDS.
template<typename TIN>
__global__ __launch_bounds__(256) void k_mmf(const TIN* __restrict__ X,
                                             const float* __restrict__ W,
                                             const float* __restrict__ dis,
                                             __half* __restrict__ Y, int n) {
    __shared__ __align__(16) __half Xs[64][72];   // 144B rows
    __shared__ __align__(16) __half Wt[64][72];   // Wt[j][k] = W[k][j]
    __shared__ float disS[64];
    int tid = threadIdx.x;
    int base = blockIdx.x * 64;
    // stage W transposed (coalesced f32 read, scalar LDS write)
    for (int i = tid; i < 4096; i += 256) {
        int k = i >> 6, j = i & 63;
        Wt[j][k] = __float2half(W[i]);
    }
    if (tid < 64) disS[tid] = (base + tid < n) ? dis[base + tid] : 0.f;
    // stage X rows as fp16
    if constexpr (sizeof(TIN) == 4) {
#pragma unroll
        for (int ii = 0; ii < 4; ++ii) {
            int i = ii * 256 + tid;
            int r = i >> 4, c4 = i & 15;
            int row = base + r;
            float4 vv = (row < n) ? ((const float4*)(X + (size_t)row * 64))[c4]
                                  : make_float4(0.f, 0.f, 0.f, 0.f);
            *(__half2*)&Xs[r][c4 * 4 + 0] = __floats2half2_rn(vv.x, vv.y);
            *(__half2*)&Xs[r][c4 * 4 + 2] = __floats2half2_rn(vv.z, vv.w);
        }
    } else {
#pragma unroll
        for (int ii = 0; ii < 2; ++ii) {
            int i = ii * 256 + tid;
            int r = i >> 3, c8 = i & 7;
            int row = base + r;
            uint4 u = {0, 0, 0, 0};
            if (row < n)
                u = *(const uint4*)((const __half*)X + (size_t)row * 64 + c8 * 8);
            *(uint4*)&Xs[r][c8 * 8] = u;
        }
    }
    __syncthreads();
    int w = tid >> 6, lane = tid & 63;
    int ar = w * 16 + (lane & 15);
    int ak = (lane >> 4) * 8;
    half8 a0 = *(const half8*)&Xs[ar][ak];
    half8 a1 = *(const half8*)&Xs[ar][32 + ak];
    f32x4 acc0 = {0.f, 0.f, 0.f, 0.f}, acc1 = acc0, acc2 = acc0, acc3 = acc0;
#define MMCOL(ACC, C) {                                                   \
        half8 b0 = *(const half8*)&Wt[(C) * 16 + (lane & 15)][ak];        \
        half8 b1 = *(const half8*)&Wt[(C) * 16 + (lane & 15)][32 + ak];   \
        ACC = __builtin_amdgcn_mfma_f32_16x16x32_f16(a0, b0, ACC, 0, 0, 0); \
        ACC = __builtin_amdgcn_mfma_f32_16x16x32_f16(a1, b1, ACC, 0, 0, 0); }
    MMCOL(acc0, 0) MMCOL(acc1, 1) MMCOL(acc2, 2) MMCOL(acc3, 3)
#undef MMCOL
    __syncthreads();                       // Wt/Xs reads done; reuse Xs for D
    // D layout: col = lane&15, row_local(in band) = (lane>>4)*4 + i
#define DST(ACC, C) {                                                     \
        _Pragma("unroll")                                                 \
        for (int i = 0; i < 4; ++i) {                                     \
            int rl = w * 16 + (lane >> 4) * 4 + i;                        \
            Xs[rl][(C) * 16 + (lane & 15)] = __float2half(ACC[i] * disS[rl]); \
        } }
    DST(acc0, 0) DST(acc1, 1) DST(acc2, 2) DST(acc3, 3)
#undef DST
    __syncthreads();
#pragma unroll
    for (int ii = 0; ii < 2; ++ii) {       // coalesced 16B stores
        int i = ii * 256 + tid;
        int r = i >> 3, c8 = i & 7;
        int row = base + r;
        if (row < n)
            *(uint4*)(Y + (size_t)row * 64 + c8 * 8) = *(const uint4*)&Xs[r][c8 * 8];
    }
}

// ---- gather, group-per-node; padded runs -> int4 csr loads, no tails ----
#define ACC8(A, U) {                                                     \
    float2 f_;                                                           \
    f_ = __half22float2(*(__half2*)&U.x); A[0] += f_.x; A[1] += f_.y;    \
    f_ = __half22float2(*(__half2*)&U.y); A[2] += f_.x; A[3] += f_.y;    \
    f_ = __half22float2(*(__half2*)&U.z); A[4] += f_.x; A[5] += f_.y;    \
    f_ = __half22float2(*(__half2*)&U.w); A[6] += f_.x; A[7] += f_.y; }

template<bool HEAD>
__global__ __launch_bounds__(256) void k_gatherg(
        const __half* __restrict__ T, const int* __restrict__ csr,
        const int* __restrict__ rowptr, const int* __restrict__ deg,
        const float* __restrict__ dis, const float* __restrict__ bias,
        const float* __restrict__ Wp, const float* __restrict__ bp,
        void* __restrict__ outv, int n) {
    int tid = threadIdx.x;
    int q = tid & 7;
    int node = blockIdx.x * 32 + (tid >> 3);
    if (node >= n) return;
    int base = rowptr[node];
    int cnt  = deg[node];                  // multiple of 4
    float dd = dis[node];
    const char* Tq = (const char*)T + q * 16;
    float a0[8], a1[8];
#pragma unroll
    for (int i = 0; i < 8; ++i) { a0[i] = 0.f; a1[i] = 0.f; }
    int j = 0;
    for (; j + 8 <= cnt; j += 8) {
        int4 c0 = *(const int4*)(csr + base + j);
        int4 c1 = *(const int4*)(csr + base + j + 4);
        uint4 u0 = *(const uint4*)(Tq + (size_t)(unsigned)c0.x);
        uint4 u1 = *(const uint4*)(Tq + (size_t)(unsigned)c0.y);
        uint4 u2 = *(const uint4*)(Tq + (size_t)(unsigned)c0.z);
        uint4 u3 = *(const uint4*)(Tq + (size_t)(unsigned)c0.w);
        uint4 u4 = *(const uint4*)(Tq + (size_t)(unsigned)c1.x);
        uint4 u5 = *(const uint4*)(Tq + (size_t)(unsigned)c1.y);
        uint4 u6 = *(const uint4*)(Tq + (size_t)(unsigned)c1.z);
        uint4 u7 = *(const uint4*)(Tq + (size_t)(unsigned)c1.w);
        ACC8(a0, u0) ACC8(a1, u1) ACC8(a0, u2) ACC8(a1, u3)
        ACC8(a0, u4) ACC8(a1, u5) ACC8(a0, u6) ACC8(a1, u7)
    }
    if (j < cnt) {
        int4 c0 = *(const int4*)(csr + base + j);
        uint4 u0 = *(const uint4*)(Tq + (size_t)(unsigned)c0.x);
        uint4 u1 = *(const uint4*)(Tq + (size_t)(unsigned)c0.y);
        uint4 u2 = *(const uint4*)(Tq + (size_t)(unsigned)c0.z);
        uint4 u3 = *(const uint4*)(Tq + (size_t)(unsigned)c0.w);
        ACC8(a0, u0) ACC8(a1, u1) ACC8(a0, u2) ACC8(a1, u3)
    }
    uint4 us = *(const uint4*)(Tq + (size_t)node * 128);   // self row
    ACC8(a1, us)
    float4 bb0 = ((const float4*)bias)[q * 2 + 0];
    float4 bb1 = ((const float4*)bias)[q * 2 + 1];
    float r[8];
    r[0] = fmaxf(dd * (a0[0] + a1[0]) + bb0.x, 0.f);
    r[1] = fmaxf(dd * (a0[1] + a1[1]) + bb0.y, 0.f);
    r[2] = fmaxf(dd * (a0[2] + a1[2]) + bb0.z, 0.f);
    r[3] = fmaxf(dd * (a0[3] + a1[3]) + bb0.w, 0.f);
    r[4] = fmaxf(dd * (a0[4] + a1[4]) + bb1.x, 0.f);
    r[5] = fmaxf(dd * (a0[5] + a1[5]) + bb1.y, 0.f);
    r[6] = fmaxf(dd * (a0[6] + a1[6]) + bb1.z, 0.f);
    r[7] = fmaxf(dd * (a0[7] + a1[7]) + bb1.w, 0.f);
    if constexpr (HEAD) {
        float4 w0 = ((const float4*)Wp)[q * 2 + 0];
        float4 w1 = ((const float4*)Wp)[q * 2 + 1];
        float s = r[0] * w0.x + r[1] * w0.y + r[2] * w0.z + r[3] * w0.w
                + r[4] * w1.x + r[5] * w1.y + r[6] * w1.z + r[7] * w1.w;
#pragma unroll
        for (int m = 1; m <= 4; m <<= 1) s += __shfl_xor(s, m);
        if (q == 0) ((float*)outv)[node] = s + bp[0];
    } else {
        __half* op = (__half*)outv + (size_t)node * 64 + q * 8;
        uint4 u;
        *(__half2*)&u.x = __floats2half2_rn(r[0], r[1]);
        *(__half2*)&u.y = __floats2half2_rn(r[2], r[3]);
        *(__half2*)&u.z = __floats2half2_rn(r[4], r[5]);
        *(__half2*)&u.w = __floats2half2_rn(r[6], r[7]);
        *(uint4*)op = u;
    }
}

extern "C" void kernel_launch(void* const* d_in, const int* in_sizes, int n_in,
                              void* d_out, int out_size, void* d_ws, size_t ws_size,
                              hipStream_t stream) {
    const float* x  = (const float*)d_in[0];
    const int*   ei = (const int*)d_in[1];
    const float* W1 = (const float*)d_in[2];
    const float* b1 = (const float*)d_in[3];
    const float* W2 = (const float*)d_in[4];
    const float* b2 = (const float*)d_in[5];
    const float* Wp = (const float*)d_in[6];
    const float* bp = (const float*)d_in[7];
    float* out = (float*)d_out;

    const int N = GNN_N, E = GNN_E;
    const int* srcv = ei;
    const int* dstv = ei + E;

    // workspace layout (bytes):
    //   hist   @ 0          : HBLK*NBUCK ints = 782,000
    //   bbase  @ 784,000    : 392 ints
    //   cbase  @ 785,600    : 392 ints
    //   rowptr @ 787,200    : N ints
    //   deg    @ 1,187,200  : N ints
    //   dis/tot@ 1,587,200  : N floats (tot aliases; dis written by bsort)
    //   csr    @ 1,987,200  : ~1.91M ints padded (7.61 MB)
    //   TA     @ 9,597,440  : (N+1)*64 fp16
    //   h1h    @ 22,410,368 : N*64 fp16
    //   TB     @ 35,210,368 : (N+1)*64 fp16
    //   part   @ 48,023,296 : E u32 (6.4 MB)   [total ~54.4 MB]
    char* ws = (char*)d_ws;
    int*    hist   = (int*)(ws + 0);
    int*    bbase  = (int*)(ws + 784000);
    int*    cbase  = (int*)(ws + 785600);
    int*    rowptr = (int*)(ws + 787200);
    int*    deg    = (int*)(ws + 1187200);
    float*  dis    = (float*)(ws + 1587200);
    int*    tot    = (int*)(ws + 1587200);
    int*    csr    = (int*)(ws + 1987200);
    __half* TA     = (__half*)(ws + 9597440);
    __half* h1h    = (__half*)(ws + 22410368);
    __half* TB     = (__half*)(ws + 35210368);
    unsigned int* part = (unsigned int*)(ws + 48023296);

    // CSR build
    k_hist <<<HBLK, 256, 0, stream>>>(dstv, hist, TA, TB);
    k_cscan<<<(NBUCK + SCTILE - 1) / SCTILE, 256, 0, stream>>>(hist, tot);
    k_btot <<<1, 512, 0, stream>>>(tot, bbase, cbase);
    k_part <<<NBLK, 256, 0, stream>>>(srcv, dstv, hist, bbase, part);
    k_bsort<<<NBUCK, 256, 0, stream>>>(part, bbase, cbase, csr, rowptr, deg, dis);

    // layer 1: TA = fp16((x@W1)*dis) ; h1h = fp16(relu(gather))
    k_mmf<float><<<(N + 63) / 64, 256, 0, stream>>>(x, W1, dis, TA, N);
    k_gatherg<false><<<(N + 31) / 32, 256, 0, stream>>>(TA, csr, rowptr, deg, dis,
                                                        b1, nullptr, nullptr, h1h, N);
    // layer 2 + head: TB = fp16((h1h@W2)*dis) ; out = head(relu(gather))
    k_mmf<__half><<<(N + 63) / 64, 256, 0, stream>>>(h1h, W2, dis, TB, N);
    k_gatherg<true><<<(N + 31) / 32, 256, 0, stream>>>(TB, csr, rowptr, deg, dis,
                                                       b2, Wp, bp, out, N);
}

// Round 13
// 127.536 us; speedup vs baseline: 2.3578x; 1.0353x over previous
//
#include <hip/hip_runtime.h>
#include <hip/hip_fp16.h>

// BusStopGNN round 13: W2 matmul fused into gather-1.
// gather-1's block ends with 32 complete h1 rows -> stage to LDS fp16 tile,
// in-block MFMA (32x64 @ 64x64), dis epilogue, coalesced TB store. Deletes
// the mmf-2 kernel, the h1h buffer, and a 12.8MB read+write pair.
// Everything else (CSR counting sort, mmf-1, head gather) unchanged.

#define GNN_N 100000
#define GNN_E 1600000
#define NBUCK 391       // ceil(N/256), bucket = dst >> 8
#define HBLK  500       // hist blocks
#define EPBH  3200      // E / HBLK, %4 == 0
#define NBLK  250       // part blocks
#define EPB   6400      // E / NBLK, %4 == 0
#define SCTILE 16
#define STAGE_CAP 4864
#define DUMMY_OFF (GNN_N * 128)   // byte offset of zero row in fp16 tables

typedef _Float16 half8 __attribute__((ext_vector_type(8)));
typedef float f32x4 __attribute__((ext_vector_type(4)));

// ---- Pass 1: per-block LDS histogram (int4 sweep) + zero-row init ----
__global__ __launch_bounds__(256) void k_hist(const int* __restrict__ dst,
                                              int* __restrict__ hist,
                                              __half* __restrict__ TA,
                                              __half* __restrict__ TB) {
    __shared__ int h[NBUCK];
    for (int i = threadIdx.x; i < NBUCK; i += 256) h[i] = 0;
    if (blockIdx.x == 0 && threadIdx.x < 16) {     // zero row N of both tables
        uint4 z = {0, 0, 0, 0};
        int t = threadIdx.x;
        __half* base = (t < 8) ? TA : TB;
        *(uint4*)((char*)base + DUMMY_OFF + (t & 7) * 16) = z;
    }
    __syncthreads();
    int b = blockIdx.x;
    int e0 = b * EPBH, e1 = min(e0 + EPBH, GNN_E);
    for (int e = e0 + threadIdx.x * 4; e < e1; e += 1024) {
        int4 d = *(const int4*)(dst + e);
        atomicAdd(&h[d.x >> 8], 1);
        atomicAdd(&h[d.y >> 8], 1);
        atomicAdd(&h[d.z >> 8], 1);
        atomicAdd(&h[d.w >> 8], 1);
    }
    __syncthreads();
    for (int i = threadIdx.x; i < NBUCK; i += 256)
        hist[b * NBUCK + i] = h[i];
}

// ---- Pass 2a: tiled column scan over HBLK rows (2 passes of 256) ----
__global__ __launch_bounds__(256) void k_cscan(int* __restrict__ hist,
                                               int* __restrict__ tot) {
    __shared__ int tile[256][SCTILE + 1];
    int k0 = blockIdx.x * SCTILE;
    int b = threadIdx.x;
    int lane = b & 63, w = b >> 6;
    int cSub = lane >> 4;
    int l16 = lane & 15;
    int col = w * 4 + cSub;
    int run = 0;
    for (int pass = 0; pass < 2; ++pass) {
        int r = pass * 256 + b;
#pragma unroll
        for (int i = 0; i < SCTILE; ++i) {
            int k = k0 + i;
            tile[b][i] = (k < NBUCK && r < HBLK) ? hist[r * NBUCK + k] : 0;
        }
        __syncthreads();
        for (int chunk = 0; chunk < 16; ++chunk) {
            int idx = chunk * 16 + l16;
            int v = tile[idx][col];
            int s = v;
#pragma unroll
            for (int o = 1; o < 16; o <<= 1) {
                int t = __shfl_up(s, o);
                if (l16 >= o) s += t;
            }
            tile[idx][col] = s - v + run;
            run += __shfl(s, lane | 15);
        }
        __syncthreads();
#pragma unroll
        for (int i = 0; i < SCTILE; ++i) {
            int k = k0 + i;
            if (k < NBUCK && r < HBLK) hist[r * NBUCK + k] = tile[b][i];
        }
        __syncthreads();
    }
    if (l16 == 0 && k0 + col < NBUCK) tot[k0 + col] = run;
}

// ---- Pass 2b: parallel scan of bucket totals -> bbase, cbase ----
__global__ __launch_bounds__(512) void k_btot(const int* __restrict__ tot,
                                              int* __restrict__ bbase,
                                              int* __restrict__ cbase) {
    __shared__ int s[512];
    int t = threadIdx.x;
    int own = (t < NBUCK) ? tot[t] : 0;
    s[t] = own;
    __syncthreads();
    for (int off = 1; off < 512; off <<= 1) {
        int v = (t >= off) ? s[t - off] : 0;
        __syncthreads();
        s[t] += v;
        __syncthreads();
    }
    if (t < NBUCK) {
        int ex = s[t] - own;
        bbase[t] = ex;
        cbase[t] = (ex & ~3) + t * 772;
    }
    if (t == 0) bbase[NBUCK] = GNN_E;
}

// ---- Pass 3: partition edges (int4); pack (dst&255)<<17 | src ----
__global__ __launch_bounds__(256) void k_part(const int* __restrict__ src,
                                              const int* __restrict__ dst,
                                              const int* __restrict__ hist,
                                              const int* __restrict__ bbase,
                                              unsigned int* __restrict__ part) {
    __shared__ int off[NBUCK];
    int b = blockIdx.x;
    for (int i = threadIdx.x; i < NBUCK; i += 256)
        off[i] = bbase[i] + hist[(2 * b) * NBUCK + i];
    __syncthreads();
    int e0 = b * EPB, e1 = min(e0 + EPB, GNN_E);
    for (int e = e0 + threadIdx.x * 4; e < e1; e += 1024) {
        int4 d = *(const int4*)(dst + e);
        int4 s = *(const int4*)(src + e);
        int sl0 = atomicAdd(&off[d.x >> 8], 1);
        part[sl0] = ((unsigned int)(d.x & 255) << 17) | (unsigned int)s.x;
        int sl1 = atomicAdd(&off[d.y >> 8], 1);
        part[sl1] = ((unsigned int)(d.y & 255) << 17) | (unsigned int)s.y;
        int sl2 = atomicAdd(&off[d.z >> 8], 1);
        part[sl2] = ((unsigned int)(d.z & 255) << 17) | (unsigned int)s.z;
        int sl3 = atomicAdd(&off[d.w >> 8], 1);
        part[sl3] = ((unsigned int)(d.w & 255) << 17) | (unsigned int)s.w;
    }
}

// ---- Pass 4: per-bucket sort, LDS-staged, 4-padded runs, parallel scan ----
__global__ __launch_bounds__(256) void k_bsort(const unsigned int* __restrict__ part,
                                               const int* __restrict__ bbase,
                                               const int* __restrict__ cbase,
                                               int* __restrict__ csr,
                                               int* __restrict__ rowptr,
                                               int* __restrict__ deg,
                                               float* __restrict__ dis) {
    __shared__ int cnt[256];
    __shared__ int pstart[256];
    __shared__ int bump[256];
    __shared__ int wtot[4];
    __shared__ unsigned int stage[STAGE_CAP];
    int k = blockIdx.x;
    int t = threadIdx.x;
    cnt[t] = 0;
    __syncthreads();
    int e0 = bbase[k], e1 = bbase[k + 1];
    int m = e1 - e0;
    bool fits = (m <= STAGE_CAP);
    for (int i = t; i < m; i += 256) {
        unsigned int p = part[e0 + i];
        if (fits) stage[i] = p;
        atomicAdd(&cnt[p >> 17], 1);
    }
    __syncthreads();
    int c = cnt[t];
    int padded = (c + 3) & ~3;
    int v = padded;
#pragma unroll
    for (int o = 1; o < 64; o <<= 1) {
        int u = __shfl_up(v, o);
        if ((t & 63) >= o) v += u;
    }
    if ((t & 63) == 63) wtot[t >> 6] = v;
    __syncthreads();
    int wb = 0;
#pragma unroll
    for (int j = 0; j < 4; ++j)
        if (j < (t >> 6)) wb += wtot[j];
    pstart[t] = wb + v - padded;
    bump[t] = pstart[t];
    __syncthreads();
    int cb = cbase[k];
    int node = k * 256 + t;
    if (node < GNN_N) {
        rowptr[node] = cb + pstart[t];
        deg[node]    = padded;
        dis[node]    = rsqrtf((float)c + 1.0f);
    }
    for (int i = t; i < m; i += 256) {
        unsigned int p = fits ? stage[i] : part[e0 + i];
        int slot = atomicAdd(&bump[p >> 17], 1);
        csr[cb + slot] = (int)(p & 0x1FFFF) << 7;
    }
    __syncthreads();
    if (node < GNN_N) {
        for (int i = c; i < padded; ++i)
            csr[cb + pstart[t] + i] = DUMMY_OFF;
    }
}

// ---- MFMA 64x64 matmul (layer 1): TA[row] = fp16((x@W1)[row]*dis[row]) ----
__global__ __launch_bounds__(256) void k_mmf(const float* __restrict__ X,
                                             const float* __restrict__ W,
                                             const float* __restrict__ dis,
                                             __half* __restrict__ Y, int n) {
    __shared__ __align__(16) __half Xs[64][72];
    __shared__ __align__(16) __half Wt[64][72];
    __shared__ float disS[64];
    int tid = threadIdx.x;
    int base = blockIdx.x * 64;
    for (int i = tid; i < 4096; i += 256) {
        int k = i >> 6, j = i & 63;
        Wt[j][k] = __float2half(W[i]);
    }
    if (tid < 64) disS[tid] = (base + tid < n) ? dis[base + tid] : 0.f;
#pragma unroll
    for (int ii = 0; ii < 4; ++ii) {
        int i = ii * 256 + tid;
        int r = i >> 4, c4 = i & 15;
        int row = base + r;
        float4 vv = (row < n) ? ((const float4*)(X + (size_t)row * 64))[c4]
                              : make_float4(0.f, 0.f, 0.f, 0.f);
        *(__half2*)&Xs[r][c4 * 4 + 0] = __floats2half2_rn(vv.x, vv.y);
        *(__half2*)&Xs[r][c4 * 4 + 2] = __floats2half2_rn(vv.z, vv.w);
    }
    __syncthreads();
    int w = tid >> 6, lane = tid & 63;
    int ar = w * 16 + (lane & 15);
    int ak = (lane >> 4) * 8;
    half8 a0 = *(const half8*)&Xs[ar][ak];
    half8 a1 = *(const half8*)&Xs[ar][32 + ak];
    f32x4 acc0 = {0.f, 0.f, 0.f, 0.f}, acc1 = acc0, acc2 = acc0, acc3 = acc0;
#define MMCOL(ACC, C) {                                                   \
        half8 b0 = *(const half8*)&Wt[(C) * 16 + (lane & 15)][ak];        \
        half8 b1 = *(const half8*)&Wt[(C) * 16 + (lane & 15)][32 + ak];   \
        ACC = __builtin_amdgcn_mfma_f32_16x16x32_f16(a0, b0, ACC, 0, 0, 0); \
        ACC = __builtin_amdgcn_mfma_f32_16x16x32_f16(a1, b1, ACC, 0, 0, 0); }
    MMCOL(acc0, 0) MMCOL(acc1, 1) MMCOL(acc2, 2) MMCOL(acc3, 3)
#undef MMCOL
    __syncthreads();
#define DST(ACC, C) {                                                     \
        _Pragma("unroll")                                                 \
        for (int i = 0; i < 4; ++i) {                                     \
            int rl = w * 16 + (lane >> 4) * 4 + i;                        \
            Xs[rl][(C) * 16 + (lane & 15)] = __float2half(ACC[i] * disS[rl]); \
        } }
    DST(acc0, 0) DST(acc1, 1) DST(acc2, 2) DST(acc3, 3)
#undef DST
    __syncthreads();
#pragma unroll
    for (int ii = 0; ii < 2; ++ii) {
        int i = ii * 256 + tid;
        int r = i >> 3, c8 = i & 7;
        int row = base + r;
        if (row < n)
            *(uint4*)(Y + (size_t)row * 64 + c8 * 8) = *(const uint4*)&Xs[r][c8 * 8];
    }
}

#define ACC8(A, U) {                                                     \
    float2 f_;                                                           \
    f_ = __half22float2(*(__half2*)&U.x); A[0] += f_.x; A[1] += f_.y;    \
    f_ = __half22float2(*(__half2*)&U.y); A[2] += f_.x; A[3] += f_.y;    \
    f_ = __half22float2(*(__half2*)&U.z); A[4] += f_.x; A[5] += f_.y;    \
    f_ = __half22float2(*(__half2*)&U.w); A[6] += f_.x; A[7] += f_.y; }

// ---- fused gather + W2 matmul: TB[i] = fp16( (relu(z_i)@W2) * dis[i] ) ----
// Phase 1: group-per-node gather of TA (8 lanes x 8ch), r = relu(...) -> LDS.
// Phase 2: 4 waves MFMA the 32x64 tile @ W2 (fp16 LDS), dis epilogue,
//          LDS-bounce coalesced store. Grid 3125*32 == N exactly (no tails).
__global__ __launch_bounds__(256) void k_gatherW2(
        const __half* __restrict__ T, const int* __restrict__ csr,
        const int* __restrict__ rowptr, const int* __restrict__ deg,
        const float* __restrict__ dis, const float* __restrict__ bias,
        const float* __restrict__ W2, __half* __restrict__ TB) {
    __shared__ __align__(16) __half Wt[64][72];   // W2^T fp16
    __shared__ __align__(16) __half Rt[32][72];   // h1 tile, then D tile
    __shared__ float disT[32];
    int tid = threadIdx.x;
    // stage W2^T (loads issue early; latency hides under gather phase)
    for (int i = tid; i < 4096; i += 256) {
        int k = i >> 6, j = i & 63;
        Wt[j][k] = __float2half(W2[i]);
    }
    int q = tid & 7;
    int nl = tid >> 3;                     // node-local 0..31
    int node = blockIdx.x * 32 + nl;       // always < N (exact grid)
    int base = rowptr[node];
    int cnt  = deg[node];                  // multiple of 4
    float dd = dis[node];
    if (q == 0) disT[nl] = dd;
    const char* Tq = (const char*)T + q * 16;
    float a0[8], a1[8];
#pragma unroll
    for (int i = 0; i < 8; ++i) { a0[i] = 0.f; a1[i] = 0.f; }
    int j = 0;
    for (; j + 8 <= cnt; j += 8) {
        int4 c0 = *(const int4*)(csr + base + j);
        int4 c1 = *(const int4*)(csr + base + j + 4);
        uint4 u0 = *(const uint4*)(Tq + (size_t)(unsigned)c0.x);
        uint4 u1 = *(const uint4*)(Tq + (size_t)(unsigned)c0.y);
        uint4 u2 = *(const uint4*)(Tq + (size_t)(unsigned)c0.z);
        uint4 u3 = *(const uint4*)(Tq + (size_t)(unsigned)c0.w);
        uint4 u4 = *(const uint4*)(Tq + (size_t)(unsigned)c1.x);
        uint4 u5 = *(const uint4*)(Tq + (size_t)(unsigned)c1.y);
        uint4 u6 = *(const uint4*)(Tq + (size_t)(unsigned)c1.z);
        uint4 u7 = *(const uint4*)(Tq + (size_t)(unsigned)c1.w);
        ACC8(a0, u0) ACC8(a1, u1) ACC8(a0, u2) ACC8(a1, u3)
        ACC8(a0, u4) ACC8(a1, u5) ACC8(a0, u6) ACC8(a1, u7)
    }
    if (j < cnt) {
        int4 c0 = *(const int4*)(csr + base + j);
        uint4 u0 = *(const uint4*)(Tq + (size_t)(unsigned)c0.x);
        uint4 u1 = *(const uint4*)(Tq + (size_t)(unsigned)c0.y);
        uint4 u2 = *(const uint4*)(Tq + (size_t)(unsigned)c0.z);
        uint4 u3 = *(const uint4*)(Tq + (size_t)(unsigned)c0.w);
        ACC8(a0, u0) ACC8(a1, u1) ACC8(a0, u2) ACC8(a1, u3)
    }
    uint4 us = *(const uint4*)(Tq + (size_t)node * 128);   // self row
    ACC8(a1, us)
    float4 bb0 = ((const float4*)bias)[q * 2 + 0];
    float4 bb1 = ((const float4*)bias)[q * 2 + 1];
    float r[8];
    r[0] = fmaxf(dd * (a0[0] + a1[0]) + bb0.x, 0.f);
    r[1] = fmaxf(dd * (a0[1] + a1[1]) + bb0.y, 0.f);
    r[2] = fmaxf(dd * (a0[2] + a1[2]) + bb0.z, 0.f);
    r[3] = fmaxf(dd * (a0[3] + a1[3]) + bb0.w, 0.f);
    r[4] = fmaxf(dd * (a0[4] + a1[4]) + bb1.x, 0.f);
    r[5] = fmaxf(dd * (a0[5] + a1[5]) + bb1.y, 0.f);
    r[6] = fmaxf(dd * (a0[6] + a1[6]) + bb1.z, 0.f);
    r[7] = fmaxf(dd * (a0[7] + a1[7]) + bb1.w, 0.f);
    uint4 u;
    *(__half2*)&u.x = __floats2half2_rn(r[0], r[1]);
    *(__half2*)&u.y = __floats2half2_rn(r[2], r[3]);
    *(__half2*)&u.z = __floats2half2_rn(r[4], r[5]);
    *(__half2*)&u.w = __floats2half2_rn(r[6], r[7]);
    *(uint4*)&Rt[nl][q * 8] = u;
    __syncthreads();                       // h1 tile + Wt ready
    // Phase 2: wave w -> rows band*16..+15, cols cg*32..+31
    int w = tid >> 6, lane = tid & 63;
    int band = w >> 1, cg = w & 1;
    int ar = band * 16 + (lane & 15);
    int ak = (lane >> 4) * 8;
    half8 fa0 = *(const half8*)&Rt[ar][ak];
    half8 fa1 = *(const half8*)&Rt[ar][32 + ak];
    f32x4 acc0 = {0.f, 0.f, 0.f, 0.f}, acc1 = acc0;
    {
        int c0 = cg * 2, c1 = cg * 2 + 1;
        half8 b00 = *(const half8*)&Wt[c0 * 16 + (lane & 15)][ak];
        half8 b01 = *(const half8*)&Wt[c0 * 16 + (lane & 15)][32 + ak];
        half8 b10 = *(const half8*)&Wt[c1 * 16 + (lane & 15)][ak];
        half8 b11 = *(const half8*)&Wt[c1 * 16 + (lane & 15)][32 + ak];
        acc0 = __builtin_amdgcn_mfma_f32_16x16x32_f16(fa0, b00, acc0, 0, 0, 0);
        acc0 = __builtin_amdgcn_mfma_f32_16x16x32_f16(fa1, b01, acc0, 0, 0, 0);
        acc1 = __builtin_amdgcn_mfma_f32_16x16x32_f16(fa0, b10, acc1, 0, 0, 0);
        acc1 = __builtin_amdgcn_mfma_f32_16x16x32_f16(fa1, b11, acc1, 0, 0, 0);
    }
    __syncthreads();                       // all A-frags consumed; reuse Rt for D
#pragma unroll
    for (int i = 0; i < 4; ++i) {
        int rl = band * 16 + (lane >> 4) * 4 + i;
        float dsc = disT[rl];
        Rt[rl][(cg * 2 + 0) * 16 + (lane & 15)] = __float2half(acc0[i] * dsc);
        Rt[rl][(cg * 2 + 1) * 16 + (lane & 15)] = __float2half(acc1[i] * dsc);
    }
    __syncthreads();
    {                                      // coalesced 16B stores of TB rows
        int r8 = tid >> 3, c8 = tid & 7;
        int row = blockIdx.x * 32 + r8;
        *(uint4*)(TB + (size_t)row * 64 + c8 * 8) = *(const uint4*)&Rt[r8][c8 * 8];
    }
}

// ---- head gather: out[i] = dot(relu(dis*(sum TB rows)+b2), Wp) + bp ----
__global__ __launch_bounds__(256) void k_gatherg(
        const __half* __restrict__ T, const int* __restrict__ csr,
        const int* __restrict__ rowptr, const int* __restrict__ deg,
        const float* __restrict__ dis, const float* __restrict__ bias,
        const float* __restrict__ Wp, const float* __restrict__ bp,
        float* __restrict__ out, int n) {
    int tid = threadIdx.x;
    int q = tid & 7;
    int node = blockIdx.x * 32 + (tid >> 3);
    if (node >= n) return;
    int base = rowptr[node];
    int cnt  = deg[node];
    float dd = dis[node];
    const char* Tq = (const char*)T + q * 16;
    float a0[8], a1[8];
#pragma unroll
    for (int i = 0; i < 8; ++i) { a0[i] = 0.f; a1[i] = 0.f; }
    int j = 0;
    for (; j + 8 <= cnt; j += 8) {
        int4 c0 = *(const int4*)(csr + base + j);
        int4 c1 = *(const int4*)(csr + base + j + 4);
        uint4 u0 = *(const uint4*)(Tq + (size_t)(unsigned)c0.x);
        uint4 u1 = *(const uint4*)(Tq + (size_t)(unsigned)c0.y);
        uint4 u2 = *(const uint4*)(Tq + (size_t)(unsigned)c0.z);
        uint4 u3 = *(const uint4*)(Tq + (size_t)(unsigned)c0.w);
        uint4 u4 = *(const uint4*)(Tq + (size_t)(unsigned)c1.x);
        uint4 u5 = *(const uint4*)(Tq + (size_t)(unsigned)c1.y);
        uint4 u6 = *(const uint4*)(Tq + (size_t)(unsigned)c1.z);
        uint4 u7 = *(const uint4*)(Tq + (size_t)(unsigned)c1.w);
        ACC8(a0, u0) ACC8(a1, u1) ACC8(a0, u2) ACC8(a1, u3)
        ACC8(a0, u4) ACC8(a1, u5) ACC8(a0, u6) ACC8(a1, u7)
    }
    if (j < cnt) {
        int4 c0 = *(const int4*)(csr + base + j);
        uint4 u0 = *(const uint4*)(Tq + (size_t)(unsigned)c0.x);
        uint4 u1 = *(const uint4*)(Tq + (size_t)(unsigned)c0.y);
        uint4 u2 = *(const uint4*)(Tq + (size_t)(unsigned)c0.z);
        uint4 u3 = *(const uint4*)(Tq + (size_t)(unsigned)c0.w);
        ACC8(a0, u0) ACC8(a1, u1) ACC8(a0, u2) ACC8(a1, u3)
    }
    uint4 us = *(const uint4*)(Tq + (size_t)node * 128);
    ACC8(a1, us)
    float4 bb0 = ((const float4*)bias)[q * 2 + 0];
    float4 bb1 = ((const float4*)bias)[q * 2 + 1];
    float r[8];
    r[0] = fmaxf(dd * (a0[0] + a1[0]) + bb0.x, 0.f);
    r[1] = fmaxf(dd * (a0[1] + a1[1]) + bb0.y, 0.f);
    r[2] = fmaxf(dd * (a0[2] + a1[2]) + bb0.z, 0.f);
    r[3] = fmaxf(dd * (a0[3] + a1[3]) + bb0.w, 0.f);
    r[4] = fmaxf(dd * (a0[4] + a1[4]) + bb1.x, 0.f);
    r[5] = fmaxf(dd * (a0[5] + a1[5]) + bb1.y, 0.f);
    r[6] = fmaxf(dd * (a0[6] + a1[6]) + bb1.z, 0.f);
    r[7] = fmaxf(dd * (a0[7] + a1[7]) + bb1.w, 0.f);
    float4 w0 = ((const float4*)Wp)[q * 2 + 0];
    float4 w1 = ((const float4*)Wp)[q * 2 + 1];
    float s = r[0] * w0.x + r[1] * w0.y + r[2] * w0.z + r[3] * w0.w
            + r[4] * w1.x + r[5] * w1.y + r[6] * w1.z + r[7] * w1.w;
#pragma unroll
    for (int m = 1; m <= 4; m <<= 1) s += __shfl_xor(s, m);
    if (q == 0) out[node] = s + bp[0];
}

extern "C" void kernel_launch(void* const* d_in, const int* in_sizes, int n_in,
                              void* d_out, int out_size, void* d_ws, size_t ws_size,
                              hipStream_t stream) {
    const float* x  = (const float*)d_in[0];
    const int*   ei = (const int*)d_in[1];
    const float* W1 = (const float*)d_in[2];
    const float* b1 = (const float*)d_in[3];
    const float* W2 = (const float*)d_in[4];
    const float* b2 = (const float*)d_in[5];
    const float* Wp = (const float*)d_in[6];
    const float* bp = (const float*)d_in[7];
    float* out = (float*)d_out;

    const int N = GNN_N, E = GNN_E;
    const int* srcv = ei;
    const int* dstv = ei + E;

    // workspace layout (bytes):
    //   hist   @ 0          : HBLK*NBUCK ints = 782,000
    //   bbase  @ 784,000    : 392 ints
    //   cbase  @ 785,600    : 392 ints
    //   rowptr @ 787,200    : N ints
    //   deg    @ 1,187,200  : N ints
    //   dis/tot@ 1,587,200  : N floats
    //   csr    @ 1,987,200  : ~1.91M ints padded (7.61 MB)
    //   TA     @ 9,597,440  : (N+1)*64 fp16 (12.8 MB)
    //   TB     @ 22,400,000 : (N+1)*64 fp16 (12.8 MB)
    //   part   @ 35,200,256 : E u32 (6.4 MB)    [total ~41.6 MB]
    char* ws = (char*)d_ws;
    int*    hist   = (int*)(ws + 0);
    int*    bbase  = (int*)(ws + 784000);
    int*    cbase  = (int*)(ws + 785600);
    int*    rowptr = (int*)(ws + 787200);
    int*    deg    = (int*)(ws + 1187200);
    float*  dis    = (float*)(ws + 1587200);
    int*    tot    = (int*)(ws + 1587200);
    int*    csr    = (int*)(ws + 1987200);
    __half* TA     = (__half*)(ws + 9597440);
    __half* TB     = (__half*)(ws + 22400000);
    unsigned int* part = (unsigned int*)(ws + 35200256);

    // CSR build
    k_hist <<<HBLK, 256, 0, stream>>>(dstv, hist, TA, TB);
    k_cscan<<<(NBUCK + SCTILE - 1) / SCTILE, 256, 0, stream>>>(hist, tot);
    k_btot <<<1, 512, 0, stream>>>(tot, bbase, cbase);
    k_part <<<NBLK, 256, 0, stream>>>(srcv, dstv, hist, bbase, part);
    k_bsort<<<NBUCK, 256, 0, stream>>>(part, bbase, cbase, csr, rowptr, deg, dis);

    // layer 1 matmul: TA = fp16((x@W1)*dis)
    k_mmf<<<(N + 63) / 64, 256, 0, stream>>>(x, W1, dis, TA, N);
    // fused layer-1 gather + layer-2 matmul: TB = fp16((relu(gather)@W2)*dis)
    k_gatherW2<<<N / 32, 256, 0, stream>>>(TA, csr, rowptr, deg, dis, b1, W2, TB);
    // layer-2 gather + head
    k_gatherg<<<(N + 31) / 32, 256, 0, stream>>>(TB, csr, rowptr, deg, dis,
                                                 b2, Wp, bp, out, N);
}